// Round 1
// baseline (333.396 us; speedup 1.0000x reference)
//
#include <hip/hip_runtime.h>
#include <hip/hip_bf16.h>
#include <math.h>

#define N_NODES 10000
#define IN_F 512
#define OUT_F 512
#define N_EDGES 160000
#define K_SPLINE 4096   // 512 dims * 8 basis fns
#define K_TOTAL 4608    // + 512 silu(base) slots
#define ALPHA 0.2f

typedef __attribute__((ext_vector_type(8))) short short8;
typedef __attribute__((ext_vector_type(4))) float f32x4;
typedef unsigned short ushort_t;

__device__ __forceinline__ unsigned short f2bf(float f) {
    unsigned int u = __float_as_uint(f);
    u += 0x7fffu + ((u >> 16) & 1u);
    return (unsigned short)(u >> 16);
}

__device__ __forceinline__ float silu_f(float x) {
    return x / (1.f + expf(-x));
}

// ---------------- K0: wa0 = W @ a[:512], wa1 = W @ a[512:] ----------------
__global__ void wa_kernel(const float* __restrict__ W, const float* __restrict__ a,
                          float* __restrict__ wa0, float* __restrict__ wa1) {
    int i = blockIdx.x;
    int l = threadIdx.x;
    float s0 = 0.f, s1 = 0.f;
    for (int o = l; o < OUT_F; o += 64) {
        float w = W[(size_t)i * OUT_F + o];
        s0 += w * a[o];
        s1 += w * a[OUT_F + o];
    }
    for (int off = 32; off > 0; off >>= 1) {
        s0 += __shfl_down(s0, off, 64);
        s1 += __shfl_down(s1, off, 64);
    }
    if (l == 0) { wa0[i] = s0; wa1[i] = s1; }
}

// ---------------- K1: s[n] = h[n]·wa0, t[n] = h[n]·wa1 ----------------
__global__ void st_kernel(const float* __restrict__ h, const float* __restrict__ wa0,
                          const float* __restrict__ wa1,
                          float* __restrict__ s, float* __restrict__ t) {
    int n = blockIdx.x;
    int l = threadIdx.x;
    const float4* hp = (const float4*)(h + (size_t)n * IN_F);
    float4 hA = hp[l], hB = hp[l + 64];
    float4 wA0 = ((const float4*)wa0)[l], wB0 = ((const float4*)wa0)[l + 64];
    float4 wA1 = ((const float4*)wa1)[l], wB1 = ((const float4*)wa1)[l + 64];
    float ss = hA.x*wA0.x + hA.y*wA0.y + hA.z*wA0.z + hA.w*wA0.w
             + hB.x*wB0.x + hB.y*wB0.y + hB.z*wB0.z + hB.w*wB0.w;
    float tt = hA.x*wA1.x + hA.y*wA1.y + hA.z*wA1.z + hA.w*wA1.w
             + hB.x*wB1.x + hB.y*wB1.y + hB.z*wB1.z + hB.w*wB1.w;
    for (int off = 32; off > 0; off >>= 1) {
        ss += __shfl_down(ss, off, 64);
        tt += __shfl_down(tt, off, 64);
    }
    if (l == 0) { s[n] = ss; t[n] = tt; }
}

// ---------------- K2: degree histogram ----------------
__global__ void deg_kernel(const int* __restrict__ ei, int* __restrict__ deg) {
    int k = blockIdx.x * 256 + threadIdx.x;
    if (k < N_EDGES) atomicAdd(&deg[ei[k]], 1);
}

// ---------------- K3: one-block exclusive scan over 10000 degrees ----------------
__global__ void scan_kernel(const int* __restrict__ deg, int* __restrict__ off,
                            int* __restrict__ cursor) {
    __shared__ int sb[1024];
    int t = threadIdx.x;
    int d[10];
    int tot = 0;
    #pragma unroll
    for (int j = 0; j < 10; ++j) {
        int idx = t * 10 + j;
        d[j] = (idx < N_NODES) ? deg[idx] : 0;
        tot += d[j];
    }
    sb[t] = tot;
    __syncthreads();
    for (int sd = 1; sd < 1024; sd <<= 1) {
        int v = (t >= sd) ? sb[t - sd] : 0;
        __syncthreads();
        sb[t] += v;
        __syncthreads();
    }
    int run = (t > 0) ? sb[t - 1] : 0;
    #pragma unroll
    for (int j = 0; j < 10; ++j) {
        int idx = t * 10 + j;
        if (idx < N_NODES) { off[idx] = run; cursor[idx] = run; }
        run += d[j];
    }
    if (t == 1023) off[N_NODES] = sb[1023];
}

// ---------------- K4: fill CSR ----------------
__global__ void fill_kernel(const int* __restrict__ ei, int* __restrict__ cursor,
                            int* __restrict__ csr_col) {
    int k = blockIdx.x * 256 + threadIdx.x;
    if (k < N_EDGES) {
        int r = ei[k];
        int c = ei[N_EDGES + k];
        int p = atomicAdd(&cursor[r], 1);
        csr_col[p] = c;
    }
}

// ---------------- K5: pack combined B (spline_w || base_w) into MFMA-fragment order ----------------
// Combined K: k in [0,4096): Bc[k][o] = spline_w[o][k>>3][k&7] = spline_w[o*4096 + k]
//             k in [4096,4608): Bc[k][o] = base_w[o][k-4096]
// Fragment layout (16x16x32 bf16): frag (k-block of 32, o-block of 16);
// lane l holds k = (l>>4)*8 + j, col o = l&15; 8 bf16 contiguous per lane.
__global__ void packB_kernel(const float* __restrict__ base_w,
                             const float* __restrict__ spline_w,
                             ushort_t* __restrict__ Bt) {
    int gid = blockIdx.x * 256 + threadIdx.x;   // 294912 total = 512 o * 576 kb8
    int o = gid / 576;
    int kb8 = gid - o * 576;
    int k0 = kb8 * 8;
    float v0, v1, v2, v3, v4, v5, v6, v7;
    if (k0 < K_SPLINE) {
        const float4* p = (const float4*)(spline_w + (size_t)o * K_SPLINE + k0);
        float4 x0 = p[0], x1 = p[1];
        v0 = x0.x; v1 = x0.y; v2 = x0.z; v3 = x0.w;
        v4 = x1.x; v5 = x1.y; v6 = x1.z; v7 = x1.w;
    } else {
        const float4* p = (const float4*)(base_w + (size_t)o * IN_F + (k0 - K_SPLINE));
        float4 x0 = p[0], x1 = p[1];
        v0 = x0.x; v1 = x0.y; v2 = x0.z; v3 = x0.w;
        v4 = x1.x; v5 = x1.y; v6 = x1.z; v7 = x1.w;
    }
    int frag = (k0 >> 5) * 32 + (o >> 4);
    int lane = ((kb8 & 3) << 4) + (o & 15);
    uint4 pk;
    pk.x = (unsigned)f2bf(v0) | ((unsigned)f2bf(v1) << 16);
    pk.y = (unsigned)f2bf(v2) | ((unsigned)f2bf(v3) << 16);
    pk.z = (unsigned)f2bf(v4) | ((unsigned)f2bf(v5) << 16);
    pk.w = (unsigned)f2bf(v6) | ((unsigned)f2bf(v7) << 16);
    *(uint4*)(Bt + ((size_t)frag * 64 + lane) * 8) = pk;
}

// ---------------- K6: per-node segment softmax + aggregation ----------------
__global__ void agg_kernel(const float* __restrict__ h, const float* __restrict__ s,
                           const float* __restrict__ t, const int* __restrict__ off,
                           const int* __restrict__ csr_col, float* __restrict__ agg) {
    __shared__ float red[4];
    int n = blockIdx.x;
    int tid = threadIdx.x;
    int wid = tid >> 6, lane = tid & 63;
    int e0 = off[n], e1 = off[n + 1];
    float sn = s[n];

    // pass 1: max
    float lm = -1e30f;
    for (int k = e0 + tid; k < e1; k += 256) {
        float v = sn + t[csr_col[k]];
        v = (v >= 0.f) ? v : ALPHA * v;
        lm = fmaxf(lm, v);
    }
    for (int o = 32; o > 0; o >>= 1) lm = fmaxf(lm, __shfl_down(lm, o, 64));
    if (lane == 0) red[wid] = lm;
    __syncthreads();
    float m = fmaxf(fmaxf(red[0], red[1]), fmaxf(red[2], red[3]));
    __syncthreads();

    // pass 2: denominator
    float ld = 0.f;
    for (int k = e0 + tid; k < e1; k += 256) {
        float v = sn + t[csr_col[k]];
        v = (v >= 0.f) ? v : ALPHA * v;
        ld += expf(v - m);
    }
    for (int o = 32; o > 0; o >>= 1) ld += __shfl_down(ld, o, 64);
    if (lane == 0) red[wid] = ld;
    __syncthreads();
    float den = red[0] + red[1] + red[2] + red[3];
    float inv = (den > 0.f) ? 1.f / den : 0.f;

    // pass 3: aggregate h[col] weighted by att; each thread owns 2 features
    float a0 = 0.f, a1 = 0.f;
    for (int k = e0; k < e1; ++k) {
        int c = csr_col[k];
        float v = sn + t[c];
        v = (v >= 0.f) ? v : ALPHA * v;
        float att = expf(v - m) * inv;
        a0 += att * h[(size_t)c * IN_F + tid];
        a1 += att * h[(size_t)c * IN_F + 256 + tid];
    }
    agg[(size_t)n * IN_F + tid] = a0;
    agg[(size_t)n * IN_F + 256 + tid] = a1;
}

// ---------------- K7: fused KAN GEMM: out[n][o] = sum_k X[n][k] * Bc[k][o] ----------------
// X[n][k] = basis(agg[n][k>>3])[k&7] for k<4096 ; silu(agg[n][k-4096]) for k>=4096.
// BM=64 rows, BN=128 cols per block; 4 waves, wave w handles 32 cols; K-step 64.
__global__ __launch_bounds__(256, 2) void kan_gemm_kernel(
    const float* __restrict__ agg, const ushort_t* __restrict__ Bt,
    float* __restrict__ out) {
    __shared__ ushort_t A_lds[64][72];  // +8 pad: bank-conflict-free b128 reads

    int bid = blockIdx.x;
    int bm = bid >> 2, bn = bid & 3;
    int tid = threadIdx.x;
    int w = tid >> 6, l = tid & 63;
    int wc = bn * 128 + w * 32;

    f32x4 acc[4][2];
    #pragma unroll
    for (int m = 0; m < 4; ++m)
        #pragma unroll
        for (int nf = 0; nf < 2; ++nf)
            acc[m][nf] = (f32x4){0.f, 0.f, 0.f, 0.f};

    int r = tid >> 2;       // expansion row 0..63
    int sub = tid & 3;
    int row = bm * 64 + r;
    if (row > N_NODES - 1) row = N_NODES - 1;
    const float* arow = agg + (size_t)row * IN_F;

    for (int kt = 0; kt < K_TOTAL; kt += 64) {
        // ---- expand A tile [64 rows][64 k] into LDS (bf16) ----
        if (kt < K_SPLINE) {
            int i0 = kt >> 3;  // 8 input dims this step
            float2 av = *(const float2*)(arow + i0 + sub * 2);
            #pragma unroll
            for (int q = 0; q < 2; ++q) {
                float x = q ? av.y : av.x;
                // closed-form uniform cubic B-spline on grid [-2.2 : 0.4 : 2.2]
                float xc = (x + 2.2f) * 2.5f;
                float fc = floorf(xc);
                int c = (int)fc;
                float u = xc - fc;
                float omu = 1.f - u;
                float u2 = u * u, u3 = u2 * u;
                float n0 = omu * omu * omu * (1.f / 6.f);
                float n1 = 0.5f * u3 - u2 + (2.f / 3.f);
                float n2 = -0.5f * u3 + 0.5f * u2 + 0.5f * u + (1.f / 6.f);
                float n3 = (1.f / 6.f) * u3;
                bool valid = (c >= 0) && (c <= 10);
                int j0 = c - 3;
                unsigned short b[8];
                #pragma unroll
                for (int jj = 0; jj < 8; ++jj) {
                    int dd = jj - j0;
                    float val = (dd == 0) ? n0 : (dd == 1) ? n1 : (dd == 2) ? n2 : (dd == 3) ? n3 : 0.f;
                    if (!valid) val = 0.f;
                    b[jj] = f2bf(val);
                }
                uint4 pk;
                pk.x = (unsigned)b[0] | ((unsigned)b[1] << 16);
                pk.y = (unsigned)b[2] | ((unsigned)b[3] << 16);
                pk.z = (unsigned)b[4] | ((unsigned)b[5] << 16);
                pk.w = (unsigned)b[6] | ((unsigned)b[7] << 16);
                *(uint4*)&A_lds[r][(sub * 2 + q) * 8] = pk;
            }
        } else {
            int i0 = kt - K_SPLINE;
            int c0 = sub * 16;
            const float* ap = arow + i0 + c0;
            #pragma unroll
            for (int hlf = 0; hlf < 2; ++hlf) {
                float4 x0 = *(const float4*)(ap + hlf * 8);
                float4 x1 = *(const float4*)(ap + hlf * 8 + 4);
                uint4 pk;
                pk.x = (unsigned)f2bf(silu_f(x0.x)) | ((unsigned)f2bf(silu_f(x0.y)) << 16);
                pk.y = (unsigned)f2bf(silu_f(x0.z)) | ((unsigned)f2bf(silu_f(x0.w)) << 16);
                pk.z = (unsigned)f2bf(silu_f(x1.x)) | ((unsigned)f2bf(silu_f(x1.y)) << 16);
                pk.w = (unsigned)f2bf(silu_f(x1.z)) | ((unsigned)f2bf(silu_f(x1.w)) << 16);
                *(uint4*)&A_lds[r][c0 + hlf * 8] = pk;
            }
        }
        __syncthreads();

        // ---- MFMA: 2 K-sub-steps of 32 ----
        #pragma unroll
        for (int ks = 0; ks < 64; ks += 32) {
            int kg = kt + ks;
            short8 bfr[2];
            #pragma unroll
            for (int nf = 0; nf < 2; ++nf) {
                size_t boff = ((size_t)((kg >> 5) * 32 + ((wc + nf * 16) >> 4)) * 64 + l) * 8;
                bfr[nf] = *(const short8*)(Bt + boff);
            }
            #pragma unroll
            for (int m = 0; m < 4; ++m) {
                short8 af = *(const short8*)&A_lds[m * 16 + (l & 15)][ks + ((l >> 4) << 3)];
                acc[m][0] = __builtin_amdgcn_mfma_f32_16x16x32_bf16(af, bfr[0], acc[m][0], 0, 0, 0);
                acc[m][1] = __builtin_amdgcn_mfma_f32_16x16x32_bf16(af, bfr[1], acc[m][1], 0, 0, 0);
            }
        }
        __syncthreads();
    }

    // ---- store: C/D layout col = l&15, row = (l>>4)*4 + reg ----
    #pragma unroll
    for (int m = 0; m < 4; ++m) {
        int row0 = bm * 64 + m * 16 + ((l >> 4) << 2);
        #pragma unroll
        for (int nf = 0; nf < 2; ++nf) {
            int colg = wc + nf * 16 + (l & 15);
            #pragma unroll
            for (int jr = 0; jr < 4; ++jr) {
                int rr = row0 + jr;
                if (rr < N_NODES) out[(size_t)rr * OUT_F + colg] = acc[m][nf][jr];
            }
        }
    }
}

extern "C" void kernel_launch(void* const* d_in, const int* in_sizes, int n_in,
                              void* d_out, int out_size, void* d_ws, size_t ws_size,
                              hipStream_t stream) {
    const float* h        = (const float*)d_in[0];
    const float* W        = (const float*)d_in[1];
    const float* a        = (const float*)d_in[2];
    const float* base_w   = (const float*)d_in[3];
    const float* spline_w = (const float*)d_in[4];
    const int*   ei       = (const int*)d_in[5];
    float* out = (float*)d_out;

    char* ws = (char*)d_ws;
    size_t cur = 0;
    auto alloc = [&](size_t bytes) -> void* {
        void* p = ws + cur;
        cur += (bytes + 255) & ~(size_t)255;
        return p;
    };
    float* wa0    = (float*)alloc(512 * 4);
    float* wa1    = (float*)alloc(512 * 4);
    float* s      = (float*)alloc(N_NODES * 4);
    float* t      = (float*)alloc(N_NODES * 4);
    int*   deg    = (int*)alloc(N_NODES * 4);
    int*   offp   = (int*)alloc((N_NODES + 1) * 4);
    int*   cursor = (int*)alloc(N_NODES * 4);
    int*   csr    = (int*)alloc(N_EDGES * 4);
    float* agg    = (float*)alloc((size_t)N_NODES * IN_F * 4);
    ushort_t* Bt  = (ushort_t*)alloc((size_t)K_TOTAL * OUT_F * 2);
    if (cur > ws_size) return;  // workspace too small — fail loudly via validation

    hipMemsetAsync(deg, 0, N_NODES * 4, stream);
    wa_kernel<<<512, 64, 0, stream>>>(W, a, wa0, wa1);
    st_kernel<<<N_NODES, 64, 0, stream>>>(h, wa0, wa1, s, t);
    deg_kernel<<<(N_EDGES + 255) / 256, 256, 0, stream>>>(ei, deg);
    scan_kernel<<<1, 1024, 0, stream>>>(deg, offp, cursor);
    fill_kernel<<<(N_EDGES + 255) / 256, 256, 0, stream>>>(ei, cursor, csr);
    packB_kernel<<<(512 * 576) / 256, 256, 0, stream>>>(base_w, spline_w, Bt);
    agg_kernel<<<N_NODES, 256, 0, stream>>>(h, s, t, offp, csr, agg);
    kan_gemm_kernel<<<157 * 4, 256, 0, stream>>>(agg, Bt, out);
}

// Round 2
// 299.887 us; speedup vs baseline: 1.1117x; 1.1117x over previous
//
#include <hip/hip_runtime.h>
#include <hip/hip_bf16.h>
#include <math.h>

#define N_NODES 10000
#define IN_F 512
#define OUT_F 512
#define N_EDGES 160000
#define K_SPLINE 4096   // 512 dims * 8 basis fns
#define K_TOTAL 4608    // + 512 silu(base) slots
#define ALPHA 0.2f

typedef __attribute__((ext_vector_type(8))) short short8;
typedef __attribute__((ext_vector_type(4))) float f32x4;
typedef unsigned short ushort_t;
typedef unsigned long long u64;

__device__ __forceinline__ unsigned short f2bf(float f) {
    unsigned int u = __float_as_uint(f);
    u += 0x7fffu + ((u >> 16) & 1u);
    return (unsigned short)(u >> 16);
}

__device__ __forceinline__ unsigned bfpair(float a, float b) {
    __hip_bfloat162 h2 = __float22bfloat162_rn(make_float2(a, b));
    return *reinterpret_cast<unsigned*>(&h2);
}

__device__ __forceinline__ float silu_f(float x) {
    return x / (1.f + expf(-x));
}

// ---------------- K0: wa0 = W @ a[:512], wa1 = W @ a[512:] ----------------
__global__ void wa_kernel(const float* __restrict__ W, const float* __restrict__ a,
                          float* __restrict__ wa0, float* __restrict__ wa1) {
    int i = blockIdx.x;
    int l = threadIdx.x;
    float s0 = 0.f, s1 = 0.f;
    for (int o = l; o < OUT_F; o += 64) {
        float w = W[(size_t)i * OUT_F + o];
        s0 += w * a[o];
        s1 += w * a[OUT_F + o];
    }
    for (int off = 32; off > 0; off >>= 1) {
        s0 += __shfl_down(s0, off, 64);
        s1 += __shfl_down(s1, off, 64);
    }
    if (l == 0) { wa0[i] = s0; wa1[i] = s1; }
}

// ---------------- K1: s[n] = h[n]·wa0, t[n] = h[n]·wa1 ----------------
__global__ void st_kernel(const float* __restrict__ h, const float* __restrict__ wa0,
                          const float* __restrict__ wa1,
                          float* __restrict__ s, float* __restrict__ t) {
    int n = blockIdx.x;
    int l = threadIdx.x;
    const float4* hp = (const float4*)(h + (size_t)n * IN_F);
    float4 hA = hp[l], hB = hp[l + 64];
    float4 wA0 = ((const float4*)wa0)[l], wB0 = ((const float4*)wa0)[l + 64];
    float4 wA1 = ((const float4*)wa1)[l], wB1 = ((const float4*)wa1)[l + 64];
    float ss = hA.x*wA0.x + hA.y*wA0.y + hA.z*wA0.z + hA.w*wA0.w
             + hB.x*wB0.x + hB.y*wB0.y + hB.z*wB0.z + hB.w*wB0.w;
    float tt = hA.x*wA1.x + hA.y*wA1.y + hA.z*wA1.z + hA.w*wA1.w
             + hB.x*wB1.x + hB.y*wB1.y + hB.z*wB1.z + hB.w*wB1.w;
    for (int off = 32; off > 0; off >>= 1) {
        ss += __shfl_down(ss, off, 64);
        tt += __shfl_down(tt, off, 64);
    }
    if (l == 0) { s[n] = ss; t[n] = tt; }
}

// ---------------- K2: degree histogram ----------------
__global__ void deg_kernel(const int* __restrict__ ei, int* __restrict__ deg) {
    int k = blockIdx.x * 256 + threadIdx.x;
    if (k < N_EDGES) atomicAdd(&deg[ei[k]], 1);
}

// ---------------- K3: one-block exclusive scan over 10000 degrees ----------------
__global__ void scan_kernel(const int* __restrict__ deg, int* __restrict__ off,
                            int* __restrict__ cursor) {
    __shared__ int sb[1024];
    int t = threadIdx.x;
    int d[10];
    int tot = 0;
    #pragma unroll
    for (int j = 0; j < 10; ++j) {
        int idx = t * 10 + j;
        d[j] = (idx < N_NODES) ? deg[idx] : 0;
        tot += d[j];
    }
    sb[t] = tot;
    __syncthreads();
    for (int sd = 1; sd < 1024; sd <<= 1) {
        int v = (t >= sd) ? sb[t - sd] : 0;
        __syncthreads();
        sb[t] += v;
        __syncthreads();
    }
    int run = (t > 0) ? sb[t - 1] : 0;
    #pragma unroll
    for (int j = 0; j < 10; ++j) {
        int idx = t * 10 + j;
        if (idx < N_NODES) { off[idx] = run; cursor[idx] = run; }
        run += d[j];
    }
    if (t == 1023) off[N_NODES] = sb[1023];
}

// ---------------- K4: fill CSR ----------------
__global__ void fill_kernel(const int* __restrict__ ei, int* __restrict__ cursor,
                            int* __restrict__ csr_col) {
    int k = blockIdx.x * 256 + threadIdx.x;
    if (k < N_EDGES) {
        int r = ei[k];
        int c = ei[N_EDGES + k];
        int p = atomicAdd(&cursor[r], 1);
        csr_col[p] = c;
    }
}

// ---------------- K5: pack combined B (spline_w || base_w) into MFMA-fragment order ----------------
__global__ void packB_kernel(const float* __restrict__ base_w,
                             const float* __restrict__ spline_w,
                             ushort_t* __restrict__ Bt) {
    int gid = blockIdx.x * 256 + threadIdx.x;   // 294912 total = 512 o * 576 kb8
    int o = gid / 576;
    int kb8 = gid - o * 576;
    int k0 = kb8 * 8;
    float v0, v1, v2, v3, v4, v5, v6, v7;
    if (k0 < K_SPLINE) {
        const float4* p = (const float4*)(spline_w + (size_t)o * K_SPLINE + k0);
        float4 x0 = p[0], x1 = p[1];
        v0 = x0.x; v1 = x0.y; v2 = x0.z; v3 = x0.w;
        v4 = x1.x; v5 = x1.y; v6 = x1.z; v7 = x1.w;
    } else {
        const float4* p = (const float4*)(base_w + (size_t)o * IN_F + (k0 - K_SPLINE));
        float4 x0 = p[0], x1 = p[1];
        v0 = x0.x; v1 = x0.y; v2 = x0.z; v3 = x0.w;
        v4 = x1.x; v5 = x1.y; v6 = x1.z; v7 = x1.w;
    }
    int frag = (k0 >> 5) * 32 + (o >> 4);
    int lane = ((kb8 & 3) << 4) + (o & 15);
    uint4 pk;
    pk.x = (unsigned)f2bf(v0) | ((unsigned)f2bf(v1) << 16);
    pk.y = (unsigned)f2bf(v2) | ((unsigned)f2bf(v3) << 16);
    pk.z = (unsigned)f2bf(v4) | ((unsigned)f2bf(v5) << 16);
    pk.w = (unsigned)f2bf(v6) | ((unsigned)f2bf(v7) << 16);
    *(uint4*)(Bt + ((size_t)frag * 64 + lane) * 8) = pk;
}

// ---------------- K6: per-node segment softmax + aggregation (+ transpose out) ----------------
__global__ void agg_kernel(const float* __restrict__ h, const float* __restrict__ s,
                           const float* __restrict__ t, const int* __restrict__ off,
                           const int* __restrict__ csr_col,
                           float* __restrict__ agg, float* __restrict__ aggT) {
    __shared__ float red[4];
    __shared__ float attL[512];
    __shared__ int colL[512];
    int n = blockIdx.x;
    int tid = threadIdx.x;
    int wid = tid >> 6, lane = tid & 63;
    int e0 = off[n], e1 = off[n + 1];
    float sn = s[n];

    // pass 1: max
    float lm = -1e30f;
    for (int k = e0 + tid; k < e1; k += 256) {
        float v = sn + t[csr_col[k]];
        v = (v >= 0.f) ? v : ALPHA * v;
        lm = fmaxf(lm, v);
    }
    for (int o = 32; o > 0; o >>= 1) lm = fmaxf(lm, __shfl_down(lm, o, 64));
    if (lane == 0) red[wid] = lm;
    __syncthreads();
    float m = fmaxf(fmaxf(red[0], red[1]), fmaxf(red[2], red[3]));
    __syncthreads();

    // pass 2: denominator
    float ld = 0.f;
    for (int k = e0 + tid; k < e1; k += 256) {
        float v = sn + t[csr_col[k]];
        v = (v >= 0.f) ? v : ALPHA * v;
        ld += expf(v - m);
    }
    for (int o = 32; o > 0; o >>= 1) ld += __shfl_down(ld, o, 64);
    if (lane == 0) red[wid] = ld;
    __syncthreads();
    float den = red[0] + red[1] + red[2] + red[3];
    float inv = (den > 0.f) ? 1.f / den : 0.f;

    // pass 3: att once per edge (LDS), then float2 gather-FMA
    float a0 = 0.f, a1 = 0.f;
    for (int e = e0; e < e1; e += 512) {
        int ce = e1 - e; if (ce > 512) ce = 512;
        __syncthreads();
        for (int j = tid; j < ce; j += 256) {
            int c = csr_col[e + j];
            float v = sn + t[c];
            v = (v >= 0.f) ? v : ALPHA * v;
            attL[j] = expf(v - m) * inv;
            colL[j] = c;
        }
        __syncthreads();
        for (int j = 0; j < ce; ++j) {
            float att = attL[j];
            float2 hv = *(const float2*)(h + (size_t)colL[j] * IN_F + 2 * tid);
            a0 = fmaf(att, hv.x, a0);
            a1 = fmaf(att, hv.y, a1);
        }
    }
    *(float2*)(agg + (size_t)n * IN_F + 2 * tid) = make_float2(a0, a1);
    aggT[(size_t)(2 * tid) * N_NODES + n] = a0;
    aggT[(size_t)(2 * tid + 1) * N_NODES + n] = a1;
}

// ---------------- K7: fused KAN GEMM ----------------
// out[n][o] = sum_k X[n][k]*Bc[k][o];  X expanded on the fly into LDS in
// MFMA-fragment-contiguous order (conflict-free writes AND reads).
// BM=64, BN=128, 256 threads (4 waves), double-buffered LDS, 1 barrier/step.
__global__ __launch_bounds__(256, 4) void kan_gemm_kernel(
    const float* __restrict__ aggT,   // [512][10000] (spline loads, coalesced)
    const float* __restrict__ agg,    // [10000][512] (base region loads)
    const ushort_t* __restrict__ Bt,
    float* __restrict__ out) {
    // [buf][frag(m*2+ks)][lane][8 bf16]
    __shared__ ushort_t A_lds[2][8][64][8];

    int tid = threadIdx.x;
    int w = tid >> 6, l = tid & 63;
    int bid = blockIdx.x;
    int bm = bid >> 2, bn = bid & 3;   // bn = XCD-residue&3 -> per-XCD B stripe stays L2-hot
    int row0 = bm * 64;

    int er = l;                         // expansion row within tile
    int erow = row0 + er; if (erow >= N_NODES) erow = N_NODES - 1;
    const float* arow = agg + (size_t)erow * IN_F;

    f32x4 acc[4][2];
    #pragma unroll
    for (int m = 0; m < 4; ++m)
        #pragma unroll
        for (int nf = 0; nf < 2; ++nf)
            acc[m][nf] = (f32x4){0.f, 0.f, 0.f, 0.f};

    int wc16 = bn * 8 + w * 2;          // 16-col fragment base for this wave

    // ---- expansion of one 64-wide K step into LDS buffer pb ----
    auto expand = [&](int kt, int pb) {
        #pragma unroll
        for (int q = 0; q < 2; ++q) {
            int d = 2 * w + q;                  // unit dim-slot 0..7
            int f = ((er >> 4) << 1) | (d >> 2);
            int lif = (er & 15) | ((d & 3) << 4);
            uint4 pk;
            if (kt < K_SPLINE) {
                int dim = (kt >> 3) + d;
                float x = aggT[(size_t)dim * N_NODES + erow];
                float xc = (x + 2.2f) * 2.5f;
                float fc = floorf(xc);
                int c = (int)fc;
                float u = xc - fc;
                float omu = 1.f - u;
                float u2 = u * u, u3 = u2 * u;
                float n0 = (1.f / 6.f) * omu * omu * omu;
                float n1 = 0.5f * u3 - u2 + (2.f / 3.f);
                float n2 = -0.5f * u3 + 0.5f * u2 + 0.5f * u + (1.f / 6.f);
                float n3 = (1.f / 6.f) * u3;
                u64 V = (u64)bfpair(n0, n1) | ((u64)bfpair(n2, n3) << 32);
                int sh = (c - 3) * 16;          // bf16-slot shift within 128-bit window
                u64 lo, hi;
                if (c < 0 || c > 10)    { lo = 0; hi = 0; }
                else if (sh >= 64)      { lo = 0; hi = V << (sh - 64); }
                else if (sh > 0)        { lo = V << sh; hi = V >> (64 - sh); }
                else if (sh == 0)       { lo = V; hi = 0; }
                else                    { lo = V >> (-sh); hi = 0; }
                pk.x = (unsigned)lo; pk.y = (unsigned)(lo >> 32);
                pk.z = (unsigned)hi; pk.w = (unsigned)(hi >> 32);
            } else {
                const float* ap = arow + (kt - K_SPLINE) + 8 * d;
                float4 x0 = *(const float4*)(ap);
                float4 x1 = *(const float4*)(ap + 4);
                pk.x = bfpair(silu_f(x0.x), silu_f(x0.y));
                pk.y = bfpair(silu_f(x0.z), silu_f(x0.w));
                pk.z = bfpair(silu_f(x1.x), silu_f(x1.y));
                pk.w = bfpair(silu_f(x1.z), silu_f(x1.w));
            }
            *(uint4*)&A_lds[pb][f][lif][0] = pk;
        }
    };

    expand(0, 0);
    int p = 0;
    for (int kt = 0; kt < K_TOTAL; kt += 64) {
        __syncthreads();                 // buf[p] writes visible; buf[p^1] reads drained
        if (kt + 64 < K_TOTAL) expand(kt + 64, p ^ 1);
        int kb = kt >> 5;
        #pragma unroll
        for (int ks = 0; ks < 2; ++ks) {
            short8 b0 = *(const short8*)(Bt + ((size_t)((kb + ks) * 32 + wc16)     * 64 + l) * 8);
            short8 b1 = *(const short8*)(Bt + ((size_t)((kb + ks) * 32 + wc16 + 1) * 64 + l) * 8);
            #pragma unroll
            for (int m = 0; m < 4; ++m) {
                short8 af = *(const short8*)&A_lds[p][m * 2 + ks][l][0];
                acc[m][0] = __builtin_amdgcn_mfma_f32_16x16x32_bf16(af, b0, acc[m][0], 0, 0, 0);
                acc[m][1] = __builtin_amdgcn_mfma_f32_16x16x32_bf16(af, b1, acc[m][1], 0, 0, 0);
            }
        }
        p ^= 1;
    }

    // ---- store: C/D layout col = l&15, row = (l>>4)*4 + reg ----
    #pragma unroll
    for (int m = 0; m < 4; ++m) {
        int r0 = row0 + m * 16 + ((l >> 4) << 2);
        #pragma unroll
        for (int nf = 0; nf < 2; ++nf) {
            int colg = bn * 128 + w * 32 + nf * 16 + (l & 15);
            #pragma unroll
            for (int jr = 0; jr < 4; ++jr) {
                int rr = r0 + jr;
                if (rr < N_NODES) out[(size_t)rr * OUT_F + colg] = acc[m][nf][jr];
            }
        }
    }
}

extern "C" void kernel_launch(void* const* d_in, const int* in_sizes, int n_in,
                              void* d_out, int out_size, void* d_ws, size_t ws_size,
                              hipStream_t stream) {
    const float* h        = (const float*)d_in[0];
    const float* W        = (const float*)d_in[1];
    const float* a        = (const float*)d_in[2];
    const float* base_w   = (const float*)d_in[3];
    const float* spline_w = (const float*)d_in[4];
    const int*   ei       = (const int*)d_in[5];
    float* out = (float*)d_out;

    char* ws = (char*)d_ws;
    size_t cur = 0;
    auto alloc = [&](size_t bytes) -> void* {
        void* p = ws + cur;
        cur += (bytes + 255) & ~(size_t)255;
        return p;
    };
    float* wa0    = (float*)alloc(512 * 4);
    float* wa1    = (float*)alloc(512 * 4);
    float* s      = (float*)alloc(N_NODES * 4);
    float* t      = (float*)alloc(N_NODES * 4);
    int*   deg    = (int*)alloc(N_NODES * 4);
    int*   offp   = (int*)alloc((N_NODES + 1) * 4);
    int*   cursor = (int*)alloc(N_NODES * 4);
    int*   csr    = (int*)alloc(N_EDGES * 4);
    float* agg    = (float*)alloc((size_t)N_NODES * IN_F * 4);
    float* aggT   = (float*)alloc((size_t)IN_F * N_NODES * 4);
    ushort_t* Bt  = (ushort_t*)alloc((size_t)K_TOTAL * OUT_F * 2);
    if (cur > ws_size) return;

    hipMemsetAsync(deg, 0, N_NODES * 4, stream);
    wa_kernel<<<512, 64, 0, stream>>>(W, a, wa0, wa1);
    st_kernel<<<N_NODES, 64, 0, stream>>>(h, wa0, wa1, s, t);
    deg_kernel<<<(N_EDGES + 255) / 256, 256, 0, stream>>>(ei, deg);
    scan_kernel<<<1, 1024, 0, stream>>>(deg, offp, cursor);
    fill_kernel<<<(N_EDGES + 255) / 256, 256, 0, stream>>>(ei, cursor, csr);
    packB_kernel<<<(512 * 576) / 256, 256, 0, stream>>>(base_w, spline_w, Bt);
    agg_kernel<<<N_NODES, 256, 0, stream>>>(h, s, t, offp, csr, agg, aggT);
    kan_gemm_kernel<<<157 * 4, 256, 0, stream>>>(aggT, agg, Bt, out);
}

// Round 3
// 231.731 us; speedup vs baseline: 1.4387x; 1.2941x over previous
//
#include <hip/hip_runtime.h>
#include <hip/hip_bf16.h>
#include <math.h>

#define N_NODES 10000
#define IN_F 512
#define OUT_F 512
#define N_EDGES 160000
#define K_SPLINE 4096   // 512 dims * 8 basis fns
#define K_TOTAL 4608    // + 512 silu(base) slots
#define ALPHA 0.2f

typedef __attribute__((ext_vector_type(8))) short short8;
typedef __attribute__((ext_vector_type(4))) float f32x4;
typedef unsigned short ushort_t;
typedef unsigned long long u64;

__device__ __forceinline__ unsigned short f2bf(float f) {
    unsigned int u = __float_as_uint(f);
    u += 0x7fffu + ((u >> 16) & 1u);
    return (unsigned short)(u >> 16);
}

__device__ __forceinline__ unsigned bfpair(float a, float b) {
    __hip_bfloat162 h2 = __float22bfloat162_rn(make_float2(a, b));
    return *reinterpret_cast<unsigned*>(&h2);
}

__device__ __forceinline__ float silu_f(float x) {
    return x / (1.f + __expf(-x));
}

// ---------------- K0: wa0 = W @ a[:512], wa1 = W @ a[512:] ----------------
__global__ void wa_kernel(const float* __restrict__ W, const float* __restrict__ a,
                          float* __restrict__ wa0, float* __restrict__ wa1) {
    int i = blockIdx.x;
    int l = threadIdx.x;
    float s0 = 0.f, s1 = 0.f;
    for (int o = l; o < OUT_F; o += 64) {
        float w = W[(size_t)i * OUT_F + o];
        s0 += w * a[o];
        s1 += w * a[OUT_F + o];
    }
    for (int off = 32; off > 0; off >>= 1) {
        s0 += __shfl_down(s0, off, 64);
        s1 += __shfl_down(s1, off, 64);
    }
    if (l == 0) { wa0[i] = s0; wa1[i] = s1; }
}

// ---------------- K1: s[n] = h[n]·wa0, t[n] = h[n]·wa1 ----------------
__global__ void st_kernel(const float* __restrict__ h, const float* __restrict__ wa0,
                          const float* __restrict__ wa1,
                          float* __restrict__ s, float* __restrict__ t) {
    int n = blockIdx.x;
    int l = threadIdx.x;
    const float4* hp = (const float4*)(h + (size_t)n * IN_F);
    float4 hA = hp[l], hB = hp[l + 64];
    float4 wA0 = ((const float4*)wa0)[l], wB0 = ((const float4*)wa0)[l + 64];
    float4 wA1 = ((const float4*)wa1)[l], wB1 = ((const float4*)wa1)[l + 64];
    float ss = hA.x*wA0.x + hA.y*wA0.y + hA.z*wA0.z + hA.w*wA0.w
             + hB.x*wB0.x + hB.y*wB0.y + hB.z*wB0.z + hB.w*wB0.w;
    float tt = hA.x*wA1.x + hA.y*wA1.y + hA.z*wA1.z + hA.w*wA1.w
             + hB.x*wB1.x + hB.y*wB1.y + hB.z*wB1.z + hB.w*wB1.w;
    for (int off = 32; off > 0; off >>= 1) {
        ss += __shfl_down(ss, off, 64);
        tt += __shfl_down(tt, off, 64);
    }
    if (l == 0) { s[n] = ss; t[n] = tt; }
}

// ---------------- K2: degree histogram ----------------
__global__ void deg_kernel(const int* __restrict__ ei, int* __restrict__ deg) {
    int k = blockIdx.x * 256 + threadIdx.x;
    if (k < N_EDGES) atomicAdd(&deg[ei[k]], 1);
}

// ---------------- K3: one-block exclusive scan over 10000 degrees ----------------
__global__ void scan_kernel(const int* __restrict__ deg, int* __restrict__ off,
                            int* __restrict__ cursor) {
    __shared__ int sb[1024];
    int t = threadIdx.x;
    int d[10];
    int tot = 0;
    #pragma unroll
    for (int j = 0; j < 10; ++j) {
        int idx = t * 10 + j;
        d[j] = (idx < N_NODES) ? deg[idx] : 0;
        tot += d[j];
    }
    sb[t] = tot;
    __syncthreads();
    for (int sd = 1; sd < 1024; sd <<= 1) {
        int v = (t >= sd) ? sb[t - sd] : 0;
        __syncthreads();
        sb[t] += v;
        __syncthreads();
    }
    int run = (t > 0) ? sb[t - 1] : 0;
    #pragma unroll
    for (int j = 0; j < 10; ++j) {
        int idx = t * 10 + j;
        if (idx < N_NODES) { off[idx] = run; cursor[idx] = run; }
        run += d[j];
    }
    if (t == 1023) off[N_NODES] = sb[1023];
}

// ---------------- K4: fill CSR ----------------
__global__ void fill_kernel(const int* __restrict__ ei, int* __restrict__ cursor,
                            int* __restrict__ csr_col) {
    int k = blockIdx.x * 256 + threadIdx.x;
    if (k < N_EDGES) {
        int r = ei[k];
        int c = ei[N_EDGES + k];
        int p = atomicAdd(&cursor[r], 1);
        csr_col[p] = c;
    }
}

// ---------------- K5: pack combined B (spline_w || base_w) into MFMA-fragment order ----------------
__global__ void packB_kernel(const float* __restrict__ base_w,
                             const float* __restrict__ spline_w,
                             ushort_t* __restrict__ Bt) {
    int gid = blockIdx.x * 256 + threadIdx.x;   // 294912 total = 512 o * 576 kb8
    int o = gid / 576;
    int kb8 = gid - o * 576;
    int k0 = kb8 * 8;
    float v0, v1, v2, v3, v4, v5, v6, v7;
    if (k0 < K_SPLINE) {
        const float4* p = (const float4*)(spline_w + (size_t)o * K_SPLINE + k0);
        float4 x0 = p[0], x1 = p[1];
        v0 = x0.x; v1 = x0.y; v2 = x0.z; v3 = x0.w;
        v4 = x1.x; v5 = x1.y; v6 = x1.z; v7 = x1.w;
    } else {
        const float4* p = (const float4*)(base_w + (size_t)o * IN_F + (k0 - K_SPLINE));
        float4 x0 = p[0], x1 = p[1];
        v0 = x0.x; v1 = x0.y; v2 = x0.z; v3 = x0.w;
        v4 = x1.x; v5 = x1.y; v6 = x1.z; v7 = x1.w;
    }
    int frag = (k0 >> 5) * 32 + (o >> 4);
    int lane = ((kb8 & 3) << 4) + (o & 15);
    uint4 pk;
    pk.x = (unsigned)f2bf(v0) | ((unsigned)f2bf(v1) << 16);
    pk.y = (unsigned)f2bf(v2) | ((unsigned)f2bf(v3) << 16);
    pk.z = (unsigned)f2bf(v4) | ((unsigned)f2bf(v5) << 16);
    pk.w = (unsigned)f2bf(v6) | ((unsigned)f2bf(v7) << 16);
    *(uint4*)(Bt + ((size_t)frag * 64 + lane) * 8) = pk;
}

// ---------------- K6: per-node segment softmax + aggregation (online softmax) ----------------
__global__ void agg_kernel(const float* __restrict__ h, const float* __restrict__ s,
                           const float* __restrict__ t, const int* __restrict__ off,
                           const int* __restrict__ csr_col,
                           float* __restrict__ agg) {
    __shared__ float red_m[4], red_d[4];
    __shared__ float attL[512];
    __shared__ int colL[512];
    int n = blockIdx.x;
    int tid = threadIdx.x;
    int wid = tid >> 6, lane = tid & 63;
    int e0 = off[n], e1 = off[n + 1];
    float sn = s[n];

    // single online pass: running (m, den)
    float m = -1e30f, den = 0.f;
    for (int k = e0 + tid; k < e1; k += 256) {
        float v = sn + t[csr_col[k]];
        v = (v >= 0.f) ? v : ALPHA * v;
        float mn = fmaxf(m, v);
        den = den * __expf(m - mn) + __expf(v - mn);
        m = mn;
    }
    for (int o = 32; o > 0; o >>= 1) {
        float m2 = __shfl_xor(m, o, 64);
        float d2 = __shfl_xor(den, o, 64);
        float mn = fmaxf(m, m2);
        den = den * __expf(m - mn) + d2 * __expf(m2 - mn);
        m = mn;
    }
    if (lane == 0) { red_m[wid] = m; red_d[wid] = den; }
    __syncthreads();
    float M = fmaxf(fmaxf(red_m[0], red_m[1]), fmaxf(red_m[2], red_m[3]));
    float D = red_d[0] * __expf(red_m[0] - M) + red_d[1] * __expf(red_m[1] - M)
            + red_d[2] * __expf(red_m[2] - M) + red_d[3] * __expf(red_m[3] - M);
    float inv = (D > 0.f) ? 1.f / D : 0.f;

    // att once per edge (LDS), then float2 gather-FMA
    float a0 = 0.f, a1 = 0.f;
    for (int e = e0; e < e1; e += 512) {
        int ce = e1 - e; if (ce > 512) ce = 512;
        __syncthreads();
        for (int j = tid; j < ce; j += 256) {
            int c = csr_col[e + j];
            float v = sn + t[c];
            v = (v >= 0.f) ? v : ALPHA * v;
            attL[j] = __expf(v - M) * inv;
            colL[j] = c;
        }
        __syncthreads();
        for (int j = 0; j < ce; ++j) {
            float att = attL[j];
            float2 hv = *(const float2*)(h + (size_t)colL[j] * IN_F + 2 * tid);
            a0 = fmaf(att, hv.x, a0);
            a1 = fmaf(att, hv.y, a1);
        }
    }
    *(float2*)(agg + (size_t)n * IN_F + 2 * tid) = make_float2(a0, a1);
}

// ---------------- K6b: tiled transpose agg[10000][512] -> aggT[512][10000] ----------------
__global__ void transpose_kernel(const float* __restrict__ agg, float* __restrict__ aggT) {
    __shared__ float tile[32][33];
    int n0 = blockIdx.x * 32, d0 = blockIdx.y * 32;
    int tx = threadIdx.x, ty = threadIdx.y;
    #pragma unroll
    for (int r = 0; r < 4; ++r) {
        int n = n0 + ty + r * 8;
        tile[ty + r * 8][tx] = (n < N_NODES) ? agg[(size_t)n * IN_F + d0 + tx] : 0.f;
    }
    __syncthreads();
    int n = n0 + tx;
    if (n < N_NODES) {
        #pragma unroll
        for (int r = 0; r < 4; ++r)
            aggT[(size_t)(d0 + ty + r * 8) * N_NODES + n] = tile[tx][ty + r * 8];
    }
}

// ---------------- K7: fused KAN GEMM, latency-decoupled ----------------
// out[n][o] = sum_k X[n][k]*Bc[k][o]; X expanded on the fly. BM=64, BN=128,
// 4 waves; double-buffered LDS; x-inputs prefetched 1 step ahead (regs),
// B fragments prefetched 1 step ahead (ping-pong regs); 1 barrier/step.
__global__ __launch_bounds__(256, 4) void kan_gemm_kernel(
    const float* __restrict__ aggT,   // [512][10000] spline x loads (coalesced)
    const float* __restrict__ agg,    // [10000][512] base region loads
    const ushort_t* __restrict__ Bt,
    float* __restrict__ out) {
    __shared__ ushort_t A_lds[2][8][64][8];   // [buf][frag][lane][8 bf16]

    int tid = threadIdx.x;
    int w = tid >> 6, l = tid & 63;
    int bid = blockIdx.x;
    int bm = bid >> 2, bn = bid & 3;
    int row0 = bm * 64;
    int erow = row0 + l; if (erow >= N_NODES) erow = N_NODES - 1;
    const float* arow = agg + (size_t)erow * IN_F;
    int wc16 = bn * 8 + w * 2;

    f32x4 acc[4][2];
    #pragma unroll
    for (int m = 0; m < 4; ++m)
        #pragma unroll
        for (int nf = 0; nf < 2; ++nf)
            acc[m][nf] = (f32x4){0.f, 0.f, 0.f, 0.f};

    float4 xv[4];       // prefetched expansion inputs for the NEXT step
    short8 br[2][4];    // ping-pong B fragments
    int p = 0;

    auto load_x = [&](int kt) {
        if (kt < K_SPLINE) {
            int dimbase = kt >> 3;
            xv[0].x = aggT[(size_t)(dimbase + 2 * w) * N_NODES + erow];
            xv[1].x = aggT[(size_t)(dimbase + 2 * w + 1) * N_NODES + erow];
        } else {
            const float* ap = arow + (kt - K_SPLINE) + 16 * w;
            xv[0] = *(const float4*)(ap);
            xv[1] = *(const float4*)(ap + 4);
            xv[2] = *(const float4*)(ap + 8);
            xv[3] = *(const float4*)(ap + 12);
        }
    };

    auto emit = [&](int kt, int pb) {   // consume xv -> LDS[pb]
        #pragma unroll
        for (int q = 0; q < 2; ++q) {
            int d = 2 * w + q;
            int f = ((l >> 4) << 1) | (d >> 2);
            int lif = (l & 15) | ((d & 3) << 4);
            uint4 pk;
            if (kt < K_SPLINE) {
                float x = xv[q].x;
                float xc = (x + 2.2f) * 2.5f;
                float fc = floorf(xc);
                int c = (int)fc;
                float u = xc - fc;
                float omu = 1.f - u;
                float u2 = u * u, u3 = u2 * u;
                float n0 = (1.f / 6.f) * omu * omu * omu;
                float n1 = 0.5f * u3 - u2 + (2.f / 3.f);
                float n2 = -0.5f * u3 + 0.5f * u2 + 0.5f * u + (1.f / 6.f);
                float n3 = (1.f / 6.f) * u3;
                u64 V = (u64)bfpair(n0, n1) | ((u64)bfpair(n2, n3) << 32);
                int sh = (c - 3) * 16;
                u64 lo, hi;
                if (c < 0 || c > 10)    { lo = 0; hi = 0; }
                else if (sh >= 64)      { lo = 0; hi = V << (sh - 64); }
                else if (sh > 0)        { lo = V << sh; hi = V >> (64 - sh); }
                else if (sh == 0)       { lo = V; hi = 0; }
                else                    { lo = V >> (-sh); hi = 0; }
                pk.x = (unsigned)lo; pk.y = (unsigned)(lo >> 32);
                pk.z = (unsigned)hi; pk.w = (unsigned)(hi >> 32);
            } else {
                float4 x0 = xv[2 * q], x1 = xv[2 * q + 1];
                pk.x = bfpair(silu_f(x0.x), silu_f(x0.y));
                pk.y = bfpair(silu_f(x0.z), silu_f(x0.w));
                pk.z = bfpair(silu_f(x1.x), silu_f(x1.y));
                pk.w = bfpair(silu_f(x1.z), silu_f(x1.w));
            }
            *(uint4*)&A_lds[pb][f][lif][0] = pk;
        }
    };

    auto loadB = [&](int kt, short8* b) {
        int kb = kt >> 5;
        #pragma unroll
        for (int ks = 0; ks < 2; ++ks) {
            b[ks * 2 + 0] = *(const short8*)(Bt + ((size_t)((kb + ks) * 32 + wc16)     * 64 + l) * 8);
            b[ks * 2 + 1] = *(const short8*)(Bt + ((size_t)((kb + ks) * 32 + wc16 + 1) * 64 + l) * 8);
        }
    };

    auto step = [&](int kt, int cur) {
        __syncthreads();    // LDS[p] writes visible; LDS[p^1] reads of prev step done
        if (kt + 64 < K_TOTAL) {
            emit(kt + 64, p ^ 1);           // pure VALU from prefetched xv
            loadB(kt + 64, br[cur ^ 1]);    // issue next-B early
        }
        if (kt + 128 < K_TOTAL) load_x(kt + 128);  // issue next-x early
        #pragma unroll
        for (int ks = 0; ks < 2; ++ks) {
            #pragma unroll
            for (int m = 0; m < 4; ++m) {
                short8 af = *(const short8*)&A_lds[p][m * 2 + ks][l][0];
                acc[m][0] = __builtin_amdgcn_mfma_f32_16x16x32_bf16(af, br[cur][ks * 2 + 0], acc[m][0], 0, 0, 0);
                acc[m][1] = __builtin_amdgcn_mfma_f32_16x16x32_bf16(af, br[cur][ks * 2 + 1], acc[m][1], 0, 0, 0);
            }
        }
        p ^= 1;
    };

    // prologue: fill LDS[0] with step 0, prefetch x(64) and B(0)
    load_x(0);
    emit(0, 0);
    load_x(64);
    loadB(0, br[0]);

    for (int kt = 0; kt < K_TOTAL; kt += 128) {
        step(kt, 0);
        step(kt + 64, 1);
    }

    // ---- store: C/D layout col = l&15, row = (l>>4)*4 + reg ----
    #pragma unroll
    for (int m = 0; m < 4; ++m) {
        int r0 = row0 + m * 16 + ((l >> 4) << 2);
        #pragma unroll
        for (int nf = 0; nf < 2; ++nf) {
            int colg = bn * 128 + w * 32 + nf * 16 + (l & 15);
            #pragma unroll
            for (int jr = 0; jr < 4; ++jr) {
                int rr = r0 + jr;
                if (rr < N_NODES) out[(size_t)rr * OUT_F + colg] = acc[m][nf][jr];
            }
        }
    }
}

extern "C" void kernel_launch(void* const* d_in, const int* in_sizes, int n_in,
                              void* d_out, int out_size, void* d_ws, size_t ws_size,
                              hipStream_t stream) {
    const float* h        = (const float*)d_in[0];
    const float* W        = (const float*)d_in[1];
    const float* a        = (const float*)d_in[2];
    const float* base_w   = (const float*)d_in[3];
    const float* spline_w = (const float*)d_in[4];
    const int*   ei       = (const int*)d_in[5];
    float* out = (float*)d_out;

    char* ws = (char*)d_ws;
    size_t cur = 0;
    auto alloc = [&](size_t bytes) -> void* {
        void* p = ws + cur;
        cur += (bytes + 255) & ~(size_t)255;
        return p;
    };
    float* wa0    = (float*)alloc(512 * 4);
    float* wa1    = (float*)alloc(512 * 4);
    float* s      = (float*)alloc(N_NODES * 4);
    float* t      = (float*)alloc(N_NODES * 4);
    int*   deg    = (int*)alloc(N_NODES * 4);
    int*   offp   = (int*)alloc((N_NODES + 1) * 4);
    int*   cursor = (int*)alloc(N_NODES * 4);
    int*   csr    = (int*)alloc(N_EDGES * 4);
    float* agg    = (float*)alloc((size_t)N_NODES * IN_F * 4);
    float* aggT   = (float*)alloc((size_t)IN_F * N_NODES * 4);
    ushort_t* Bt  = (ushort_t*)alloc((size_t)K_TOTAL * OUT_F * 2);
    if (cur > ws_size) return;

    hipMemsetAsync(deg, 0, N_NODES * 4, stream);
    wa_kernel<<<512, 64, 0, stream>>>(W, a, wa0, wa1);
    st_kernel<<<N_NODES, 64, 0, stream>>>(h, wa0, wa1, s, t);
    deg_kernel<<<(N_EDGES + 255) / 256, 256, 0, stream>>>(ei, deg);
    scan_kernel<<<1, 1024, 0, stream>>>(deg, offp, cursor);
    fill_kernel<<<(N_EDGES + 255) / 256, 256, 0, stream>>>(ei, cursor, csr);
    packB_kernel<<<(512 * 576) / 256, 256, 0, stream>>>(base_w, spline_w, Bt);
    agg_kernel<<<N_NODES, 256, 0, stream>>>(h, s, t, offp, csr, agg);
    transpose_kernel<<<dim3(313, 16), dim3(32, 8), 0, stream>>>(agg, aggT);
    kan_gemm_kernel<<<157 * 4, 256, 0, stream>>>(aggT, agg, Bt, out);
}

// Round 4
// 172.993 us; speedup vs baseline: 1.9272x; 1.3395x over previous
//
#include <hip/hip_runtime.h>
#include <hip/hip_bf16.h>
#include <math.h>

#define N_NODES 10000
#define IN_F 512
#define OUT_F 512
#define N_EDGES 160000
#define K_SPLINE 4096   // 512 dims * 8 basis fns
#define K_TOTAL 4608    // + 512 silu(base) slots
#define NBK 144         // K fragment-blocks (4608/32)
#define NBM 628         // M fragment-blocks (10048/16)
#define ALPHA 0.2f

typedef __attribute__((ext_vector_type(8))) short short8;
typedef __attribute__((ext_vector_type(4))) float f32x4;
typedef unsigned short ushort_t;
typedef unsigned long long u64;

__device__ __forceinline__ unsigned short f2bf(float f) {
    unsigned int u = __float_as_uint(f);
    u += 0x7fffu + ((u >> 16) & 1u);
    return (unsigned short)(u >> 16);
}

__device__ __forceinline__ unsigned bfpair(float a, float b) {
    __hip_bfloat162 h2 = __float22bfloat162_rn(make_float2(a, b));
    return *reinterpret_cast<unsigned*>(&h2);
}

__device__ __forceinline__ float silu_f(float x) {
    return x / (1.f + __expf(-x));
}

// spline window: 8 packed bf16 (one-hot shifted cubic pieces) for scalar x
__device__ __forceinline__ uint4 spline_window(float x) {
    float xc = (x + 2.2f) * 2.5f;
    float fc = floorf(xc);
    int c = (int)fc;
    float u = xc - fc;
    float omu = 1.f - u;
    float u2 = u * u, u3 = u2 * u;
    float n0 = (1.f / 6.f) * omu * omu * omu;
    float n1 = 0.5f * u3 - u2 + (2.f / 3.f);
    float n2 = -0.5f * u3 + 0.5f * u2 + 0.5f * u + (1.f / 6.f);
    float n3 = (1.f / 6.f) * u3;
    u64 V = (u64)bfpair(n0, n1) | ((u64)bfpair(n2, n3) << 32);
    int sh = (c - 3) * 16;
    u64 lo, hi;
    if (c < 0 || c > 10)    { lo = 0; hi = 0; }
    else if (sh >= 64)      { lo = 0; hi = V << (sh - 64); }
    else if (sh > 0)        { lo = V << sh; hi = V >> (64 - sh); }
    else if (sh == 0)       { lo = V; hi = 0; }
    else                    { lo = V >> (-sh); hi = 0; }
    uint4 pk;
    pk.x = (unsigned)lo; pk.y = (unsigned)(lo >> 32);
    pk.z = (unsigned)hi; pk.w = (unsigned)(hi >> 32);
    return pk;
}

// ---------------- K0: wa0 = W @ a[:512], wa1 = W @ a[512:] ----------------
__global__ void wa_kernel(const float* __restrict__ W, const float* __restrict__ a,
                          float* __restrict__ wa0, float* __restrict__ wa1) {
    int i = blockIdx.x;
    int l = threadIdx.x;
    float s0 = 0.f, s1 = 0.f;
    for (int o = l; o < OUT_F; o += 64) {
        float w = W[(size_t)i * OUT_F + o];
        s0 += w * a[o];
        s1 += w * a[OUT_F + o];
    }
    for (int off = 32; off > 0; off >>= 1) {
        s0 += __shfl_down(s0, off, 64);
        s1 += __shfl_down(s1, off, 64);
    }
    if (l == 0) { wa0[i] = s0; wa1[i] = s1; }
}

// ---------------- K1: s[n] = h[n]·wa0, t[n] = h[n]·wa1 ----------------
__global__ void st_kernel(const float* __restrict__ h, const float* __restrict__ wa0,
                          const float* __restrict__ wa1,
                          float* __restrict__ s, float* __restrict__ t) {
    int n = blockIdx.x;
    int l = threadIdx.x;
    const float4* hp = (const float4*)(h + (size_t)n * IN_F);
    float4 hA = hp[l], hB = hp[l + 64];
    float4 wA0 = ((const float4*)wa0)[l], wB0 = ((const float4*)wa0)[l + 64];
    float4 wA1 = ((const float4*)wa1)[l], wB1 = ((const float4*)wa1)[l + 64];
    float ss = hA.x*wA0.x + hA.y*wA0.y + hA.z*wA0.z + hA.w*wA0.w
             + hB.x*wB0.x + hB.y*wB0.y + hB.z*wB0.z + hB.w*wB0.w;
    float tt = hA.x*wA1.x + hA.y*wA1.y + hA.z*wA1.z + hA.w*wA1.w
             + hB.x*wB1.x + hB.y*wB1.y + hB.z*wB1.z + hB.w*wB1.w;
    for (int off = 32; off > 0; off >>= 1) {
        ss += __shfl_down(ss, off, 64);
        tt += __shfl_down(tt, off, 64);
    }
    if (l == 0) { s[n] = ss; t[n] = tt; }
}

// ---------------- K2: degree histogram ----------------
__global__ void deg_kernel(const int* __restrict__ ei, int* __restrict__ deg) {
    int k = blockIdx.x * 256 + threadIdx.x;
    if (k < N_EDGES) atomicAdd(&deg[ei[k]], 1);
}

// ---------------- K3: one-block exclusive scan over 10000 degrees ----------------
__global__ void scan_kernel(const int* __restrict__ deg, int* __restrict__ off,
                            int* __restrict__ cursor) {
    __shared__ int sb[1024];
    int t = threadIdx.x;
    int d[10];
    int tot = 0;
    #pragma unroll
    for (int j = 0; j < 10; ++j) {
        int idx = t * 10 + j;
        d[j] = (idx < N_NODES) ? deg[idx] : 0;
        tot += d[j];
    }
    sb[t] = tot;
    __syncthreads();
    for (int sd = 1; sd < 1024; sd <<= 1) {
        int v = (t >= sd) ? sb[t - sd] : 0;
        __syncthreads();
        sb[t] += v;
        __syncthreads();
    }
    int run = (t > 0) ? sb[t - 1] : 0;
    #pragma unroll
    for (int j = 0; j < 10; ++j) {
        int idx = t * 10 + j;
        if (idx < N_NODES) { off[idx] = run; cursor[idx] = run; }
        run += d[j];
    }
    if (t == 1023) off[N_NODES] = sb[1023];
}

// ---------------- K4: fill CSR ----------------
__global__ void fill_kernel(const int* __restrict__ ei, int* __restrict__ cursor,
                            int* __restrict__ csr_col) {
    int k = blockIdx.x * 256 + threadIdx.x;
    if (k < N_EDGES) {
        int r = ei[k];
        int c = ei[N_EDGES + k];
        int p = atomicAdd(&cursor[r], 1);
        csr_col[p] = c;
    }
}

// ---------------- K5: pack combined B (spline_w || base_w) into MFMA fragment order ----------------
__global__ void packB_kernel(const float* __restrict__ base_w,
                             const float* __restrict__ spline_w,
                             ushort_t* __restrict__ Bt) {
    int gid = blockIdx.x * 256 + threadIdx.x;   // 294912 = 512 o * 576 kb8
    int o = gid / 576;
    int kb8 = gid - o * 576;
    int k0 = kb8 * 8;
    float4 x0, x1;
    if (k0 < K_SPLINE) {
        const float4* p = (const float4*)(spline_w + (size_t)o * K_SPLINE + k0);
        x0 = p[0]; x1 = p[1];
    } else {
        const float4* p = (const float4*)(base_w + (size_t)o * IN_F + (k0 - K_SPLINE));
        x0 = p[0]; x1 = p[1];
    }
    int frag = (k0 >> 5) * 32 + (o >> 4);
    int lane = ((kb8 & 3) << 4) + (o & 15);
    uint4 pk;
    pk.x = bfpair(x0.x, x0.y);
    pk.y = bfpair(x0.z, x0.w);
    pk.z = bfpair(x1.x, x1.y);
    pk.w = bfpair(x1.z, x1.w);
    *(uint4*)(Bt + ((size_t)frag * 64 + lane) * 8) = pk;
}

// ---------------- K5b: h -> bf16 cast ----------------
__global__ void hcast_kernel(const float* __restrict__ h, ushort_t* __restrict__ hb) {
    int id = blockIdx.x * 256 + threadIdx.x;  // 8 elems each; 5.12M total
    const float4* p = (const float4*)(h + (size_t)id * 8);
    float4 a0 = p[0], a1 = p[1];
    uint4 pk;
    pk.x = bfpair(a0.x, a0.y);
    pk.y = bfpair(a0.z, a0.w);
    pk.z = bfpair(a1.x, a1.y);
    pk.w = bfpair(a1.z, a1.w);
    *(uint4*)(hb + (size_t)id * 8) = pk;
}

// ---------------- K6: per-node segment softmax + aggregation (bf16 gather) ----------------
__global__ void agg_kernel(const ushort_t* __restrict__ hb, const float* __restrict__ s,
                           const float* __restrict__ t, const int* __restrict__ off,
                           const int* __restrict__ csr_col,
                           float* __restrict__ agg) {
    __shared__ float red_m[4], red_d[4];
    __shared__ float attL[512];
    __shared__ int colL[512];
    int n = blockIdx.x;
    int tid = threadIdx.x;
    int wid = tid >> 6, lane = tid & 63;
    int e0 = off[n], e1 = off[n + 1];
    float sn = s[n];

    float m = -1e30f, den = 0.f;
    for (int k = e0 + tid; k < e1; k += 256) {
        float v = sn + t[csr_col[k]];
        v = (v >= 0.f) ? v : ALPHA * v;
        float mn = fmaxf(m, v);
        den = den * __expf(m - mn) + __expf(v - mn);
        m = mn;
    }
    for (int o = 32; o > 0; o >>= 1) {
        float m2 = __shfl_xor(m, o, 64);
        float d2 = __shfl_xor(den, o, 64);
        float mn = fmaxf(m, m2);
        den = den * __expf(m - mn) + d2 * __expf(m2 - mn);
        m = mn;
    }
    if (lane == 0) { red_m[wid] = m; red_d[wid] = den; }
    __syncthreads();
    float M = fmaxf(fmaxf(red_m[0], red_m[1]), fmaxf(red_m[2], red_m[3]));
    float D = red_d[0] * __expf(red_m[0] - M) + red_d[1] * __expf(red_m[1] - M)
            + red_d[2] * __expf(red_m[2] - M) + red_d[3] * __expf(red_m[3] - M);
    float inv = (D > 0.f) ? 1.f / D : 0.f;

    float a0 = 0.f, a1 = 0.f;
    for (int e = e0; e < e1; e += 512) {
        int ce = e1 - e; if (ce > 512) ce = 512;
        __syncthreads();
        for (int j = tid; j < ce; j += 256) {
            int c = csr_col[e + j];
            float v = sn + t[c];
            v = (v >= 0.f) ? v : ALPHA * v;
            attL[j] = __expf(v - M) * inv;
            colL[j] = c;
        }
        __syncthreads();
        for (int j = 0; j < ce; ++j) {
            float att = attL[j];
            unsigned u = *(const unsigned*)(hb + (size_t)colL[j] * IN_F + 2 * tid);
            float lo = __uint_as_float(u << 16);
            float hi = __uint_as_float(u & 0xffff0000u);
            a0 = fmaf(att, lo, a0);
            a1 = fmaf(att, hi, a1);
        }
    }
    *(float2*)(agg + (size_t)n * IN_F + 2 * tid) = make_float2(a0, a1);
}

// ---------------- K6f: f32-gather agg (fallback path only) ----------------
__global__ void agg_kernel_f32(const float* __restrict__ h, const float* __restrict__ s,
                               const float* __restrict__ t, const int* __restrict__ off,
                               const int* __restrict__ csr_col,
                               float* __restrict__ agg) {
    __shared__ float red_m[4], red_d[4];
    __shared__ float attL[512];
    __shared__ int colL[512];
    int n = blockIdx.x;
    int tid = threadIdx.x;
    int wid = tid >> 6, lane = tid & 63;
    int e0 = off[n], e1 = off[n + 1];
    float sn = s[n];
    float m = -1e30f, den = 0.f;
    for (int k = e0 + tid; k < e1; k += 256) {
        float v = sn + t[csr_col[k]];
        v = (v >= 0.f) ? v : ALPHA * v;
        float mn = fmaxf(m, v);
        den = den * __expf(m - mn) + __expf(v - mn);
        m = mn;
    }
    for (int o = 32; o > 0; o >>= 1) {
        float m2 = __shfl_xor(m, o, 64);
        float d2 = __shfl_xor(den, o, 64);
        float mn = fmaxf(m, m2);
        den = den * __expf(m - mn) + d2 * __expf(m2 - mn);
        m = mn;
    }
    if (lane == 0) { red_m[wid] = m; red_d[wid] = den; }
    __syncthreads();
    float M = fmaxf(fmaxf(red_m[0], red_m[1]), fmaxf(red_m[2], red_m[3]));
    float D = red_d[0] * __expf(red_m[0] - M) + red_d[1] * __expf(red_m[1] - M)
            + red_d[2] * __expf(red_m[2] - M) + red_d[3] * __expf(red_m[3] - M);
    float inv = (D > 0.f) ? 1.f / D : 0.f;
    float a0 = 0.f, a1 = 0.f;
    for (int e = e0; e < e1; e += 512) {
        int ce = e1 - e; if (ce > 512) ce = 512;
        __syncthreads();
        for (int j = tid; j < ce; j += 256) {
            int c = csr_col[e + j];
            float v = sn + t[c];
            v = (v >= 0.f) ? v : ALPHA * v;
            attL[j] = __expf(v - M) * inv;
            colL[j] = c;
        }
        __syncthreads();
        for (int j = 0; j < ce; ++j) {
            float att = attL[j];
            float2 hv = *(const float2*)(h + (size_t)colL[j] * IN_F + 2 * tid);
            a0 = fmaf(att, hv.x, a0);
            a1 = fmaf(att, hv.y, a1);
        }
    }
    *(float2*)(agg + (size_t)n * IN_F + 2 * tid) = make_float2(a0, a1);
}

// ---------------- K7a: expansion -> fragment-packed bf16 A (92.6 MB) ----------------
// Xf[(nb*144+kb)*64 + l] (16B per lane): row n = nb*16 + (l&15),
// kb<128: dim = kb*4 + (l>>4), 8 spline basis values of agg[n][dim];
// kb>=128: i0 = (kb-128)*32 + (l>>4)*8, 8 silus of agg[n][i0..+7].
__global__ void expand_kernel(const float* __restrict__ agg, ushort_t* __restrict__ Xf) {
    int id = blockIdx.x * 256 + threadIdx.x;
    int l = id & 63;
    int fid = id >> 6;
    int nb = fid / NBK;
    int kb = fid - nb * NBK;
    int n = nb * 16 + (l & 15);
    uint4 pk = make_uint4(0u, 0u, 0u, 0u);
    if (n < N_NODES) {
        if (kb < 128) {
            int dim = kb * 4 + (l >> 4);
            pk = spline_window(agg[(size_t)n * IN_F + dim]);
        } else {
            const float* ap = agg + (size_t)n * IN_F + (kb - 128) * 32 + (l >> 4) * 8;
            float4 x0 = *(const float4*)ap;
            float4 x1 = *(const float4*)(ap + 4);
            pk.x = bfpair(silu_f(x0.x), silu_f(x0.y));
            pk.y = bfpair(silu_f(x0.z), silu_f(x0.w));
            pk.z = bfpair(silu_f(x1.x), silu_f(x1.y));
            pk.w = bfpair(silu_f(x1.z), silu_f(x1.w));
        }
    }
    *(uint4*)(Xf + (size_t)id * 8) = pk;
}

// ---------------- K7b: streaming GEMM, A via global_load_lds, B direct ----------------
// BM=64, BN=128, 4 waves. Grid 640, XCD-swizzled: 4 bn-siblings of one bm on
// the same XCD (d mod 8 equal) -> A tile HBM-fetched once, L2-hit 3x.
__global__ __launch_bounds__(256, 2) void kan_gemm2(
    const ushort_t* __restrict__ Xf, const ushort_t* __restrict__ Bt,
    float* __restrict__ out) {
    __shared__ ushort_t A_lds[2][2][4][64][8];   // [buf][ks][m][lane][8]

    int d = blockIdx.x;
    int g = d >> 5, r = d & 31;
    int bm = g * 8 + (r & 7), bn = r >> 3;
    if (bm >= 157) return;
    int tid = threadIdx.x, w = tid >> 6, l = tid & 63;
    int wc16 = bn * 8 + w * 2;

    f32x4 acc[4][2];
    #pragma unroll
    for (int m = 0; m < 4; ++m)
        #pragma unroll
        for (int nf = 0; nf < 2; ++nf)
            acc[m][nf] = (f32x4){0.f, 0.f, 0.f, 0.f};

    short8 b0[4], b1[4];

    auto stage = [&](int kb, int pb) {
        #pragma unroll
        for (int ks = 0; ks < 2; ++ks) {
            const ushort_t* src = Xf + (((size_t)(bm * 4 + w) * NBK + kb + ks) * 64 + l) * 8;
            __builtin_amdgcn_global_load_lds(
                (const __attribute__((address_space(1))) unsigned int*)src,
                (__attribute__((address_space(3))) unsigned int*)&A_lds[pb][ks][w][0][0],
                16, 0, 0);
        }
    };
    auto loadB = [&](int kb, short8* b) {
        #pragma unroll
        for (int ks = 0; ks < 2; ++ks) {
            b[ks * 2 + 0] = *(const short8*)(Bt + ((size_t)((kb + ks) * 32 + wc16)     * 64 + l) * 8);
            b[ks * 2 + 1] = *(const short8*)(Bt + ((size_t)((kb + ks) * 32 + wc16 + 1) * 64 + l) * 8);
        }
    };
    auto compute = [&](int pb, short8* b) {
        #pragma unroll
        for (int ks = 0; ks < 2; ++ks)
            #pragma unroll
            for (int m = 0; m < 4; ++m) {
                short8 af = *(const short8*)&A_lds[pb][ks][m][l][0];
                acc[m][0] = __builtin_amdgcn_mfma_f32_16x16x32_bf16(af, b[ks * 2 + 0], acc[m][0], 0, 0, 0);
                acc[m][1] = __builtin_amdgcn_mfma_f32_16x16x32_bf16(af, b[ks * 2 + 1], acc[m][1], 0, 0, 0);
            }
    };

    stage(0, 0);
    loadB(0, b0);
    asm volatile("s_waitcnt vmcnt(0)" ::: "memory");
    __syncthreads();
    for (int it = 0; it < 72; it += 2) {
        stage(2 * it + 2, 1);                    // it+1 < 72 always here
        loadB(2 * it + 2, b1);
        compute(0, b0);
        asm volatile("s_waitcnt vmcnt(0)" ::: "memory");
        __syncthreads();
        if (it + 2 < 72) { stage(2 * it + 4, 0); loadB(2 * it + 4, b0); }
        compute(1, b1);
        asm volatile("s_waitcnt vmcnt(0)" ::: "memory");
        __syncthreads();
    }

    #pragma unroll
    for (int m = 0; m < 4; ++m) {
        int r0 = bm * 64 + m * 16 + ((l >> 4) << 2);
        #pragma unroll
        for (int nf = 0; nf < 2; ++nf) {
            int colg = bn * 128 + w * 32 + nf * 16 + (l & 15);
            #pragma unroll
            for (int jr = 0; jr < 4; ++jr) {
                int rr = r0 + jr;
                if (rr < N_NODES) out[(size_t)rr * OUT_F + colg] = acc[m][nf][jr];
            }
        }
    }
}

// ---------------- fallback (R3) fused GEMM + transpose ----------------
__global__ void transpose_kernel(const float* __restrict__ agg, float* __restrict__ aggT) {
    __shared__ float tile[32][33];
    int n0 = blockIdx.x * 32, d0 = blockIdx.y * 32;
    int tx = threadIdx.x, ty = threadIdx.y;
    #pragma unroll
    for (int r = 0; r < 4; ++r) {
        int n = n0 + ty + r * 8;
        tile[ty + r * 8][tx] = (n < N_NODES) ? agg[(size_t)n * IN_F + d0 + tx] : 0.f;
    }
    __syncthreads();
    int n = n0 + tx;
    if (n < N_NODES) {
        #pragma unroll
        for (int r = 0; r < 4; ++r)
            aggT[(size_t)(d0 + ty + r * 8) * N_NODES + n] = tile[tx][ty + r * 8];
    }
}

__global__ __launch_bounds__(256, 4) void kan_gemm_kernel(
    const float* __restrict__ aggT, const float* __restrict__ agg,
    const ushort_t* __restrict__ Bt, float* __restrict__ out) {
    __shared__ ushort_t A_lds[2][8][64][8];
    int tid = threadIdx.x;
    int w = tid >> 6, l = tid & 63;
    int bid = blockIdx.x;
    int bm = bid >> 2, bn = bid & 3;
    int row0 = bm * 64;
    int erow = row0 + l; if (erow >= N_NODES) erow = N_NODES - 1;
    const float* arow = agg + (size_t)erow * IN_F;
    int wc16 = bn * 8 + w * 2;
    f32x4 acc[4][2];
    #pragma unroll
    for (int m = 0; m < 4; ++m)
        #pragma unroll
        for (int nf = 0; nf < 2; ++nf)
            acc[m][nf] = (f32x4){0.f, 0.f, 0.f, 0.f};
    float4 xv[4];
    short8 br[2][4];
    int p = 0;
    auto load_x = [&](int kt) {
        if (kt < K_SPLINE) {
            int dimbase = kt >> 3;
            xv[0].x = aggT[(size_t)(dimbase + 2 * w) * N_NODES + erow];
            xv[1].x = aggT[(size_t)(dimbase + 2 * w + 1) * N_NODES + erow];
        } else {
            const float* ap = arow + (kt - K_SPLINE) + 16 * w;
            xv[0] = *(const float4*)(ap);
            xv[1] = *(const float4*)(ap + 4);
            xv[2] = *(const float4*)(ap + 8);
            xv[3] = *(const float4*)(ap + 12);
        }
    };
    auto emit = [&](int kt, int pb) {
        #pragma unroll
        for (int q = 0; q < 2; ++q) {
            int dd = 2 * w + q;
            int f = ((l >> 4) << 1) | (dd >> 2);
            int lif = (l & 15) | ((dd & 3) << 4);
            uint4 pk;
            if (kt < K_SPLINE) {
                pk = spline_window(xv[q].x);
            } else {
                float4 x0 = xv[2 * q], x1 = xv[2 * q + 1];
                pk.x = bfpair(silu_f(x0.x), silu_f(x0.y));
                pk.y = bfpair(silu_f(x0.z), silu_f(x0.w));
                pk.z = bfpair(silu_f(x1.x), silu_f(x1.y));
                pk.w = bfpair(silu_f(x1.z), silu_f(x1.w));
            }
            *(uint4*)&A_lds[pb][f][lif][0] = pk;
        }
    };
    auto loadB = [&](int kt, short8* b) {
        int kb = kt >> 5;
        #pragma unroll
        for (int ks = 0; ks < 2; ++ks) {
            b[ks * 2 + 0] = *(const short8*)(Bt + ((size_t)((kb + ks) * 32 + wc16)     * 64 + l) * 8);
            b[ks * 2 + 1] = *(const short8*)(Bt + ((size_t)((kb + ks) * 32 + wc16 + 1) * 64 + l) * 8);
        }
    };
    auto step = [&](int kt, int cur) {
        __syncthreads();
        if (kt + 64 < K_TOTAL) {
            emit(kt + 64, p ^ 1);
            loadB(kt + 64, br[cur ^ 1]);
        }
        if (kt + 128 < K_TOTAL) load_x(kt + 128);
        #pragma unroll
        for (int ks = 0; ks < 2; ++ks) {
            #pragma unroll
            for (int m = 0; m < 4; ++m) {
                short8 af = *(const short8*)&A_lds[p][m * 2 + ks][l][0];
                acc[m][0] = __builtin_amdgcn_mfma_f32_16x16x32_bf16(af, br[cur][ks * 2 + 0], acc[m][0], 0, 0, 0);
                acc[m][1] = __builtin_amdgcn_mfma_f32_16x16x32_bf16(af, br[cur][ks * 2 + 1], acc[m][1], 0, 0, 0);
            }
        }
        p ^= 1;
    };
    load_x(0);
    emit(0, 0);
    load_x(64);
    loadB(0, br[0]);
    for (int kt = 0; kt < K_TOTAL; kt += 128) {
        step(kt, 0);
        step(kt + 64, 1);
    }
    #pragma unroll
    for (int m = 0; m < 4; ++m) {
        int r0 = row0 + m * 16 + ((l >> 4) << 2);
        #pragma unroll
        for (int nf = 0; nf < 2; ++nf) {
            int colg = bn * 128 + w * 32 + nf * 16 + (l & 15);
            #pragma unroll
            for (int jr = 0; jr < 4; ++jr) {
                int rr = r0 + jr;
                if (rr < N_NODES) out[(size_t)rr * OUT_F + colg] = acc[m][nf][jr];
            }
        }
    }
}

extern "C" void kernel_launch(void* const* d_in, const int* in_sizes, int n_in,
                              void* d_out, int out_size, void* d_ws, size_t ws_size,
                              hipStream_t stream) {
    const float* h        = (const float*)d_in[0];
    const float* W        = (const float*)d_in[1];
    const float* a        = (const float*)d_in[2];
    const float* base_w   = (const float*)d_in[3];
    const float* spline_w = (const float*)d_in[4];
    const int*   ei       = (const int*)d_in[5];
    float* out = (float*)d_out;

    char* ws = (char*)d_ws;
    size_t cur = 0;
    auto alloc = [&](size_t bytes) -> void* {
        void* p = ws + cur;
        cur += (bytes + 255) & ~(size_t)255;
        return p;
    };
    float* wa0    = (float*)alloc(512 * 4);
    float* wa1    = (float*)alloc(512 * 4);
    float* s      = (float*)alloc(N_NODES * 4);
    float* t      = (float*)alloc(N_NODES * 4);
    int*   deg    = (int*)alloc(N_NODES * 4);
    int*   offp   = (int*)alloc((N_NODES + 1) * 4);
    int*   cursor = (int*)alloc(N_NODES * 4);
    int*   csr    = (int*)alloc(N_EDGES * 4);
    float* agg    = (float*)alloc((size_t)N_NODES * IN_F * 4);
    ushort_t* Bt  = (ushort_t*)alloc((size_t)K_TOTAL * OUT_F * 2);
    size_t fixed = cur;

    // main path extras
    size_t hb_b = (size_t)N_NODES * IN_F * 2;
    size_t xf_b = (size_t)NBM * NBK * 64 * 16;
    bool main_path = (fixed + ((hb_b + 255) & ~(size_t)255) + xf_b) <= ws_size;

    hipMemsetAsync(deg, 0, N_NODES * 4, stream);
    wa_kernel<<<512, 64, 0, stream>>>(W, a, wa0, wa1);
    st_kernel<<<N_NODES, 64, 0, stream>>>(h, wa0, wa1, s, t);
    deg_kernel<<<(N_EDGES + 255) / 256, 256, 0, stream>>>(ei, deg);
    scan_kernel<<<1, 1024, 0, stream>>>(deg, offp, cursor);
    fill_kernel<<<(N_EDGES + 255) / 256, 256, 0, stream>>>(ei, cursor, csr);
    packB_kernel<<<(512 * 576) / 256, 256, 0, stream>>>(base_w, spline_w, Bt);

    if (main_path) {
        ushort_t* hb = (ushort_t*)alloc(hb_b);
        ushort_t* Xf = (ushort_t*)alloc(xf_b);
        hcast_kernel<<<(N_NODES * IN_F / 8 + 255) / 256, 256, 0, stream>>>(h, hb);
        agg_kernel<<<N_NODES, 256, 0, stream>>>(hb, s, t, offp, csr, agg);
        expand_kernel<<<NBM * NBK * 64 / 256, 256, 0, stream>>>(agg, Xf);
        kan_gemm2<<<640, 256, 0, stream>>>(Xf, Bt, out);
    } else {
        float* aggT = (float*)alloc((size_t)IN_F * N_NODES * 4);
        if (cur > ws_size) return;
        agg_kernel_f32<<<N_NODES, 256, 0, stream>>>(h, s, t, offp, csr, agg);
        transpose_kernel<<<dim3(313, 16), dim3(32, 8), 0, stream>>>(agg, aggT);
        kan_gemm_kernel<<<157 * 4, 256, 0, stream>>>(aggT, agg, Bt, out);
    }
}

// Round 5
// 170.418 us; speedup vs baseline: 1.9563x; 1.0151x over previous
//
#include <hip/hip_runtime.h>
#include <hip/hip_bf16.h>
#include <math.h>

#define N_NODES 10000
#define IN_F 512
#define OUT_F 512
#define N_EDGES 160000
#define K_SPLINE 4096   // 512 dims * 8 basis fns
#define K_TOTAL 4608    // + 512 silu(base) slots
#define NBK 144         // K fragment-blocks (4608/32)
#define NBM 628         // M fragment-blocks (10048/16)
#define ALPHA 0.2f

typedef __attribute__((ext_vector_type(8))) short short8;
typedef __attribute__((ext_vector_type(4))) float f32x4;
typedef unsigned short ushort_t;
typedef unsigned long long u64;

#define WAITVM(N) asm volatile("s_waitcnt vmcnt(" #N ")" ::: "memory")

__device__ __forceinline__ unsigned bfpair(float a, float b) {
    __hip_bfloat162 h2 = __float22bfloat162_rn(make_float2(a, b));
    return *reinterpret_cast<unsigned*>(&h2);
}
__device__ __forceinline__ float bflo(unsigned u) { return __uint_as_float(u << 16); }
__device__ __forceinline__ float bfhi(unsigned u) { return __uint_as_float(u & 0xffff0000u); }

__device__ __forceinline__ float silu_f(float x) {
    return x / (1.f + __expf(-x));
}

// spline window: 8 packed bf16 (one-hot shifted cubic pieces) for scalar x
__device__ __forceinline__ uint4 spline_window(float x) {
    float xc = (x + 2.2f) * 2.5f;
    float fc = floorf(xc);
    int c = (int)fc;
    float u = xc - fc;
    float omu = 1.f - u;
    float u2 = u * u, u3 = u2 * u;
    float n0 = (1.f / 6.f) * omu * omu * omu;
    float n1 = 0.5f * u3 - u2 + (2.f / 3.f);
    float n2 = -0.5f * u3 + 0.5f * u2 + 0.5f * u + (1.f / 6.f);
    float n3 = (1.f / 6.f) * u3;
    u64 V = (u64)bfpair(n0, n1) | ((u64)bfpair(n2, n3) << 32);
    int sh = (c - 3) * 16;
    u64 lo, hi;
    if (c < 0 || c > 10)    { lo = 0; hi = 0; }
    else if (sh >= 64)      { lo = 0; hi = V << (sh - 64); }
    else if (sh > 0)        { lo = V << sh; hi = V >> (64 - sh); }
    else if (sh == 0)       { lo = V; hi = 0; }
    else                    { lo = V >> (-sh); hi = 0; }
    uint4 pk;
    pk.x = (unsigned)lo; pk.y = (unsigned)(lo >> 32);
    pk.z = (unsigned)hi; pk.w = (unsigned)(hi >> 32);
    return pk;
}

// ---------------- L1: fused wa + packB + hcast + deg (all independent) ----------------
__global__ void fused1_kernel(const float* __restrict__ W, const float* __restrict__ a,
                              float* __restrict__ wa0, float* __restrict__ wa1,
                              const float* __restrict__ base_w, const float* __restrict__ spline_w,
                              ushort_t* __restrict__ Bt,
                              const float* __restrict__ h, ushort_t* __restrict__ hb,
                              const int* __restrict__ ei, int* __restrict__ deg) {
    int b = blockIdx.x;
    int tid = threadIdx.x;
    if (b < 128) {
        // wa: 4 W-rows per block, one wave each
        int w = tid >> 6, l = tid & 63;
        int i = b * 4 + w;
        float s0 = 0.f, s1 = 0.f;
        #pragma unroll
        for (int oo = 0; oo < 8; ++oo) {
            int o = l + oo * 64;
            float wv = W[(size_t)i * OUT_F + o];
            s0 += wv * a[o];
            s1 += wv * a[OUT_F + o];
        }
        #pragma unroll
        for (int off = 32; off > 0; off >>= 1) {
            s0 += __shfl_down(s0, off, 64);
            s1 += __shfl_down(s1, off, 64);
        }
        if (l == 0) { wa0[i] = s0; wa1[i] = s1; }
    } else if (b < 1280) {
        // packB: combined (spline_w || base_w) -> MFMA fragment order
        int gid = (b - 128) * 256 + tid;        // 294912 = 512 o * 576 kb8
        int o = gid / 576;
        int kb8 = gid - o * 576;
        int k0 = kb8 * 8;
        float4 x0, x1;
        if (k0 < K_SPLINE) {
            const float4* p = (const float4*)(spline_w + (size_t)o * K_SPLINE + k0);
            x0 = p[0]; x1 = p[1];
        } else {
            const float4* p = (const float4*)(base_w + (size_t)o * IN_F + (k0 - K_SPLINE));
            x0 = p[0]; x1 = p[1];
        }
        int frag = (k0 >> 5) * 32 + (o >> 4);
        int lane = ((kb8 & 3) << 4) + (o & 15);
        uint4 pk;
        pk.x = bfpair(x0.x, x0.y);
        pk.y = bfpair(x0.z, x0.w);
        pk.z = bfpair(x1.x, x1.y);
        pk.w = bfpair(x1.z, x1.w);
        *(uint4*)(Bt + ((size_t)frag * 64 + lane) * 8) = pk;
    } else if (b < 3780) {
        // hcast: h -> bf16
        int id = (b - 1280) * 256 + tid;        // 640000 total, 8 elems each
        const float4* p = (const float4*)(h + (size_t)id * 8);
        float4 a0 = p[0], a1 = p[1];
        uint4 pk;
        pk.x = bfpair(a0.x, a0.y);
        pk.y = bfpair(a0.z, a0.w);
        pk.z = bfpair(a1.x, a1.y);
        pk.w = bfpair(a1.z, a1.w);
        *(uint4*)(hb + (size_t)id * 8) = pk;
    } else {
        // deg histogram
        int k = (b - 3780) * 256 + tid;
        if (k < N_EDGES) atomicAdd(&deg[ei[k]], 1);
    }
}

// ---------------- L2: fused st (s,t projections) + scan ----------------
__global__ void fused2_kernel(const float* __restrict__ h, const float* __restrict__ wa0,
                              const float* __restrict__ wa1,
                              float* __restrict__ s, float* __restrict__ t,
                              const int* __restrict__ deg, int* __restrict__ off,
                              int* __restrict__ cursor) {
    __shared__ int sb[256];
    int b = blockIdx.x;
    int tid = threadIdx.x;
    if (b < 2500) {
        // st: 4 nodes/block, one wave each
        int w = tid >> 6, l = tid & 63;
        int n = b * 4 + w;
        const float4* hp = (const float4*)(h + (size_t)n * IN_F);
        float4 hA = hp[l], hB = hp[l + 64];
        float4 wA0 = ((const float4*)wa0)[l], wB0 = ((const float4*)wa0)[l + 64];
        float4 wA1 = ((const float4*)wa1)[l], wB1 = ((const float4*)wa1)[l + 64];
        float ss = hA.x*wA0.x + hA.y*wA0.y + hA.z*wA0.z + hA.w*wA0.w
                 + hB.x*wB0.x + hB.y*wB0.y + hB.z*wB0.z + hB.w*wB0.w;
        float tt = hA.x*wA1.x + hA.y*wA1.y + hA.z*wA1.z + hA.w*wA1.w
                 + hB.x*wB1.x + hB.y*wB1.y + hB.z*wB1.z + hB.w*wB1.w;
        #pragma unroll
        for (int o = 32; o > 0; o >>= 1) {
            ss += __shfl_down(ss, o, 64);
            tt += __shfl_down(tt, o, 64);
        }
        if (l == 0) { s[n] = ss; t[n] = tt; }
    } else {
        // scan: 256 threads, 40 degrees each
        int d[40];
        int tot = 0;
        #pragma unroll
        for (int j = 0; j < 40; ++j) {
            int idx = tid * 40 + j;
            d[j] = (idx < N_NODES) ? deg[idx] : 0;
            tot += d[j];
        }
        sb[tid] = tot;
        __syncthreads();
        for (int sd = 1; sd < 256; sd <<= 1) {
            int v = (tid >= sd) ? sb[tid - sd] : 0;
            __syncthreads();
            sb[tid] += v;
            __syncthreads();
        }
        int run = (tid > 0) ? sb[tid - 1] : 0;
        #pragma unroll
        for (int j = 0; j < 40; ++j) {
            int idx = tid * 40 + j;
            if (idx < N_NODES) { off[idx] = run; cursor[idx] = run; }
            run += d[j];
        }
        if (tid == 255) off[N_NODES] = sb[255];
    }
}

// ---------------- L3: fill CSR ----------------
__global__ void fill_kernel(const int* __restrict__ ei, int* __restrict__ cursor,
                            int* __restrict__ csr_col) {
    int k = blockIdx.x * 256 + threadIdx.x;
    if (k < N_EDGES) {
        int r = ei[k];
        int c = ei[N_EDGES + k];
        int p = atomicAdd(&cursor[r], 1);
        csr_col[p] = c;
    }
}

// ---------------- L4: segment softmax + aggregation, wave-per-node ----------------
__global__ __launch_bounds__(256) void agg_kernel(
    const ushort_t* __restrict__ hb, const float* __restrict__ s,
    const float* __restrict__ t, const int* __restrict__ off,
    const int* __restrict__ csr, float* __restrict__ agg) {
    int w = threadIdx.x >> 6, l = threadIdx.x & 63;
    int n = blockIdx.x * 4 + w;
    int e0 = off[n], e1 = off[n + 1];
    float sn = s[n];

    // online (m, den) over edges, strided by lane
    float m = -1e30f, den = 0.f;
    for (int k = e0 + l; k < e1; k += 64) {
        float v = sn + t[csr[k]];
        v = (v >= 0.f) ? v : ALPHA * v;
        float mn = fmaxf(m, v);
        den = den * __expf(m - mn) + __expf(v - mn);
        m = mn;
    }
    #pragma unroll
    for (int o = 1; o < 64; o <<= 1) {
        float m2 = __shfl_xor(m, o, 64);
        float d2 = __shfl_xor(den, o, 64);
        float mn = fmaxf(m, m2);
        den = den * __expf(m - mn) + d2 * __expf(m2 - mn);
        m = mn;
    }
    float inv = (den > 0.f) ? 1.f / den : 0.f;

    // gather: each lane owns 8 features; per-edge att/col broadcast via shfl
    float acc[8] = {0.f, 0.f, 0.f, 0.f, 0.f, 0.f, 0.f, 0.f};
    const ushort_t* hbl = hb + l * 8;
    for (int base = e0; base < e1; base += 64) {
        int cnt = e1 - base; if (cnt > 64) cnt = 64;
        int c = 0; float att = 0.f;
        if (l < cnt) {
            c = csr[base + l];
            float v = sn + t[c];
            v = (v >= 0.f) ? v : ALPHA * v;
            att = __expf(v - m) * inv;
        }
        #pragma unroll 2
        for (int j = 0; j < cnt; ++j) {
            float aj = __shfl(att, j, 64);
            int cj = __shfl(c, j, 64);
            uint4 u = *(const uint4*)(hbl + (size_t)cj * IN_F);
            acc[0] = fmaf(aj, bflo(u.x), acc[0]);
            acc[1] = fmaf(aj, bfhi(u.x), acc[1]);
            acc[2] = fmaf(aj, bflo(u.y), acc[2]);
            acc[3] = fmaf(aj, bfhi(u.y), acc[3]);
            acc[4] = fmaf(aj, bflo(u.z), acc[4]);
            acc[5] = fmaf(aj, bfhi(u.z), acc[5]);
            acc[6] = fmaf(aj, bflo(u.w), acc[6]);
            acc[7] = fmaf(aj, bfhi(u.w), acc[7]);
        }
    }
    float* arow = agg + (size_t)n * IN_F + l * 8;
    *(float4*)arow       = make_float4(acc[0], acc[1], acc[2], acc[3]);
    *(float4*)(arow + 4) = make_float4(acc[4], acc[5], acc[6], acc[7]);
}

// ---------------- L5: expansion -> fragment-packed bf16 A (92.6 MB) ----------------
__global__ void expand_kernel(const float* __restrict__ agg, ushort_t* __restrict__ Xf) {
    int id = blockIdx.x * 256 + threadIdx.x;
    int l = id & 63;
    int fid = id >> 6;
    int nb = fid / NBK;
    int kb = fid - nb * NBK;
    int n = nb * 16 + (l & 15);
    uint4 pk = make_uint4(0u, 0u, 0u, 0u);
    if (n < N_NODES) {
        if (kb < 128) {
            int dim = kb * 4 + (l >> 4);
            pk = spline_window(agg[(size_t)n * IN_F + dim]);
        } else {
            const float* ap = agg + (size_t)n * IN_F + (kb - 128) * 32 + (l >> 4) * 8;
            float4 x0 = *(const float4*)ap;
            float4 x1 = *(const float4*)(ap + 4);
            pk.x = bfpair(silu_f(x0.x), silu_f(x0.y));
            pk.y = bfpair(silu_f(x0.z), silu_f(x0.w));
            pk.z = bfpair(silu_f(x1.x), silu_f(x1.y));
            pk.w = bfpair(silu_f(x1.z), silu_f(x1.w));
        }
    }
    *(uint4*)(Xf + (size_t)id * 8) = pk;
}

// ---------------- L6: streaming GEMM, 4-deep LDS pipeline, counted vmcnt ----------------
// BM=64, BN=128, 4 waves. 72 K-steps of 64. stage(j) issued at step j-3;
// vmcnt(8) mid-loop (never 0); raw s_barrier + sched_barrier; setprio on MFMA.
__global__ __launch_bounds__(256, 2) void kan_gemm2(
    const ushort_t* __restrict__ Xf, const ushort_t* __restrict__ Bt,
    float* __restrict__ out) {
    __shared__ ushort_t A_lds[4][2][4][64][8];   // 32 KB: [buf][ks][m][lane][8]

    int d = blockIdx.x;
    int g = d >> 5, r = d & 31;
    int bm = g * 8 + (r & 7), bn = r >> 3;      // 4 bn-siblings share XCD -> A L2-hot
    if (bm >= 157) return;
    int tid = threadIdx.x, w = tid >> 6, l = tid & 63;
    int wc16 = bn * 8 + w * 2;

    f32x4 acc[4][2];
    #pragma unroll
    for (int m = 0; m < 4; ++m)
        #pragma unroll
        for (int nf = 0; nf < 2; ++nf)
            acc[m][nf] = (f32x4){0.f, 0.f, 0.f, 0.f};

    short8 brA[4], brB[4];

    auto stage = [&](int j, int pb) {
        #pragma unroll
        for (int ks = 0; ks < 2; ++ks) {
            const ushort_t* src = Xf + (((size_t)(bm * 4 + w) * NBK + 2 * j + ks) * 64 + l) * 8;
            __builtin_amdgcn_global_load_lds(
                (const __attribute__((address_space(1))) unsigned int*)src,
                (__attribute__((address_space(3))) unsigned int*)&A_lds[pb][ks][w][0][0],
                16, 0, 0);
        }
    };
    auto loadB = [&](int j, short8 (&b)[4]) {
        int kb = 2 * j;
        #pragma unroll
        for (int ks = 0; ks < 2; ++ks) {
            b[ks * 2 + 0] = *(const short8*)(Bt + ((size_t)((kb + ks) * 32 + wc16)     * 64 + l) * 8);
            b[ks * 2 + 1] = *(const short8*)(Bt + ((size_t)((kb + ks) * 32 + wc16 + 1) * 64 + l) * 8);
        }
    };
    auto compute = [&](int pb, short8 (&b)[4]) {
        __builtin_amdgcn_s_setprio(1);
        #pragma unroll
        for (int ks = 0; ks < 2; ++ks)
            #pragma unroll
            for (int m = 0; m < 4; ++m) {
                short8 af = *(const short8*)&A_lds[pb][ks][m][l][0];
                acc[m][0] = __builtin_amdgcn_mfma_f32_16x16x32_bf16(af, b[ks * 2 + 0], acc[m][0], 0, 0, 0);
                acc[m][1] = __builtin_amdgcn_mfma_f32_16x16x32_bf16(af, b[ks * 2 + 1], acc[m][1], 0, 0, 0);
            }
        __builtin_amdgcn_s_setprio(0);
    };

    // prologue: 3 stages in flight + first B
    stage(0, 0); stage(1, 1); stage(2, 2);
    loadB(0, brA);

    for (int j = 0; j < 70; j += 2) {
        WAITVM(8);                               // forces stage(j); keeps j+1,j+2 in flight
        __builtin_amdgcn_s_barrier();
        __builtin_amdgcn_sched_barrier(0);
        loadB(j + 1, brB);
        stage(j + 3, (j + 3) & 3);
        compute(j & 3, brA);

        WAITVM(8);
        __builtin_amdgcn_s_barrier();
        __builtin_amdgcn_sched_barrier(0);
        loadB(j + 2, brA);
        if (j + 4 < 72) stage(j + 4, (j + 4) & 3);
        compute((j + 1) & 3, brB);
    }
    // j = 70
    WAITVM(6);
    __builtin_amdgcn_s_barrier();
    __builtin_amdgcn_sched_barrier(0);
    loadB(71, brB);
    compute(2, brA);
    // j = 71
    WAITVM(4);
    __builtin_amdgcn_s_barrier();
    __builtin_amdgcn_sched_barrier(0);
    compute(3, brB);

    // store: C/D layout col = l&15, row = (l>>4)*4 + reg
    #pragma unroll
    for (int m = 0; m < 4; ++m) {
        int r0 = bm * 64 + m * 16 + ((l >> 4) << 2);
        #pragma unroll
        for (int nf = 0; nf < 2; ++nf) {
            int colg = bn * 128 + w * 32 + nf * 16 + (l & 15);
            #pragma unroll
            for (int jr = 0; jr < 4; ++jr) {
                int rr = r0 + jr;
                if (rr < N_NODES) out[(size_t)rr * OUT_F + colg] = acc[m][nf][jr];
            }
        }
    }
}

extern "C" void kernel_launch(void* const* d_in, const int* in_sizes, int n_in,
                              void* d_out, int out_size, void* d_ws, size_t ws_size,
                              hipStream_t stream) {
    const float* h        = (const float*)d_in[0];
    const float* W        = (const float*)d_in[1];
    const float* a        = (const float*)d_in[2];
    const float* base_w   = (const float*)d_in[3];
    const float* spline_w = (const float*)d_in[4];
    const int*   ei       = (const int*)d_in[5];
    float* out = (float*)d_out;

    char* ws = (char*)d_ws;
    size_t cur = 0;
    auto alloc = [&](size_t bytes) -> void* {
        void* p = ws + cur;
        cur += (bytes + 255) & ~(size_t)255;
        return p;
    };
    float* wa0    = (float*)alloc(512 * 4);
    float* wa1    = (float*)alloc(512 * 4);
    float* s      = (float*)alloc(N_NODES * 4);
    float* t      = (float*)alloc(N_NODES * 4);
    int*   deg    = (int*)alloc(N_NODES * 4);
    int*   offp   = (int*)alloc((N_NODES + 1) * 4);
    int*   cursor = (int*)alloc(N_NODES * 4);
    int*   csr    = (int*)alloc(N_EDGES * 4);
    float* agg    = (float*)alloc((size_t)N_NODES * IN_F * 4);
    ushort_t* Bt  = (ushort_t*)alloc((size_t)K_TOTAL * OUT_F * 2);
    ushort_t* hb  = (ushort_t*)alloc((size_t)N_NODES * IN_F * 2);
    ushort_t* Xf  = (ushort_t*)alloc((size_t)NBM * NBK * 64 * 16);
    if (cur > ws_size) return;   // known sufficient (R4 ran this path)

    hipMemsetAsync(deg, 0, N_NODES * 4, stream);
    fused1_kernel<<<4405, 256, 0, stream>>>(W, a, wa0, wa1, base_w, spline_w, Bt, h, hb, ei, deg);
    fused2_kernel<<<2501, 256, 0, stream>>>(h, wa0, wa1, s, t, deg, offp, cursor);
    fill_kernel<<<(N_EDGES + 255) / 256, 256, 0, stream>>>(ei, cursor, csr);
    agg_kernel<<<2500, 256, 0, stream>>>(hb, s, t, offp, csr, agg);
    expand_kernel<<<NBM * NBK * 64 / 256, 256, 0, stream>>>(agg, Xf);
    kan_gemm2<<<640, 256, 0, stream>>>(Xf, Bt, out);
}

// Round 6
// 168.269 us; speedup vs baseline: 1.9813x; 1.0128x over previous
//
#include <hip/hip_runtime.h>
#include <hip/hip_bf16.h>
#include <math.h>

#define N_NODES 10000
#define IN_F 512
#define OUT_F 512
#define N_EDGES 160000
#define K_SPLINE 4096   // 512 dims * 8 basis fns
#define K_TOTAL 4608    // + 512 silu(base) slots
#define NBK 144         // K fragment-blocks (4608/32)
#define NBM 628         // M fragment-blocks (10048/16)
#define ALPHA 0.2f

typedef __attribute__((ext_vector_type(8))) short short8;
typedef __attribute__((ext_vector_type(4))) float f32x4;
typedef unsigned short ushort_t;
typedef unsigned long long u64;

__device__ __forceinline__ unsigned bfpair(float a, float b) {
    __hip_bfloat162 h2 = __float22bfloat162_rn(make_float2(a, b));
    return *reinterpret_cast<unsigned*>(&h2);
}
__device__ __forceinline__ float bflo(unsigned u) { return __uint_as_float(u << 16); }
__device__ __forceinline__ float bfhi(unsigned u) { return __uint_as_float(u & 0xffff0000u); }

__device__ __forceinline__ float silu_f(float x) {
    return x / (1.f + __expf(-x));
}

// spline window: 8 packed bf16 (one-hot shifted cubic pieces) for scalar x
__device__ __forceinline__ uint4 spline_window(float x) {
    float xc = (x + 2.2f) * 2.5f;
    float fc = floorf(xc);
    int c = (int)fc;
    float u = xc - fc;
    float omu = 1.f - u;
    float u2 = u * u, u3 = u2 * u;
    float n0 = (1.f / 6.f) * omu * omu * omu;
    float n1 = 0.5f * u3 - u2 + (2.f / 3.f);
    float n2 = -0.5f * u3 + 0.5f * u2 + 0.5f * u + (1.f / 6.f);
    float n3 = (1.f / 6.f) * u3;
    u64 V = (u64)bfpair(n0, n1) | ((u64)bfpair(n2, n3) << 32);
    int sh = (c - 3) * 16;
    u64 lo, hi;
    if (c < 0 || c > 10)    { lo = 0; hi = 0; }
    else if (sh >= 64)      { lo = 0; hi = V << (sh - 64); }
    else if (sh > 0)        { lo = V << sh; hi = V >> (64 - sh); }
    else if (sh == 0)       { lo = V; hi = 0; }
    else                    { lo = V >> (-sh); hi = 0; }
    uint4 pk;
    pk.x = (unsigned)lo; pk.y = (unsigned)(lo >> 32);
    pk.z = (unsigned)hi; pk.w = (unsigned)(hi >> 32);
    return pk;
}

// ---------------- L1: fused wa + packB + hcast + deg (all independent) ----------------
__global__ void fused1_kernel(const float* __restrict__ W, const float* __restrict__ a,
                              float* __restrict__ wa0, float* __restrict__ wa1,
                              const float* __restrict__ base_w, const float* __restrict__ spline_w,
                              ushort_t* __restrict__ Bt,
                              const float* __restrict__ h, ushort_t* __restrict__ hb,
                              const int* __restrict__ ei, int* __restrict__ deg) {
    int b = blockIdx.x;
    int tid = threadIdx.x;
    if (b < 128) {
        int w = tid >> 6, l = tid & 63;
        int i = b * 4 + w;
        float s0 = 0.f, s1 = 0.f;
        #pragma unroll
        for (int oo = 0; oo < 8; ++oo) {
            int o = l + oo * 64;
            float wv = W[(size_t)i * OUT_F + o];
            s0 += wv * a[o];
            s1 += wv * a[OUT_F + o];
        }
        #pragma unroll
        for (int off = 32; off > 0; off >>= 1) {
            s0 += __shfl_down(s0, off, 64);
            s1 += __shfl_down(s1, off, 64);
        }
        if (l == 0) { wa0[i] = s0; wa1[i] = s1; }
    } else if (b < 1280) {
        int gid = (b - 128) * 256 + tid;        // 294912 = 512 o * 576 kb8
        int o = gid / 576;
        int kb8 = gid - o * 576;
        int k0 = kb8 * 8;
        float4 x0, x1;
        if (k0 < K_SPLINE) {
            const float4* p = (const float4*)(spline_w + (size_t)o * K_SPLINE + k0);
            x0 = p[0]; x1 = p[1];
        } else {
            const float4* p = (const float4*)(base_w + (size_t)o * IN_F + (k0 - K_SPLINE));
            x0 = p[0]; x1 = p[1];
        }
        int frag = (k0 >> 5) * 32 + (o >> 4);
        int lane = ((kb8 & 3) << 4) + (o & 15);
        uint4 pk;
        pk.x = bfpair(x0.x, x0.y);
        pk.y = bfpair(x0.z, x0.w);
        pk.z = bfpair(x1.x, x1.y);
        pk.w = bfpair(x1.z, x1.w);
        *(uint4*)(Bt + ((size_t)frag * 64 + lane) * 8) = pk;
    } else if (b < 3780) {
        int id = (b - 1280) * 256 + tid;        // 640000 total, 8 elems each
        const float4* p = (const float4*)(h + (size_t)id * 8);
        float4 a0 = p[0], a1 = p[1];
        uint4 pk;
        pk.x = bfpair(a0.x, a0.y);
        pk.y = bfpair(a0.z, a0.w);
        pk.z = bfpair(a1.x, a1.y);
        pk.w = bfpair(a1.z, a1.w);
        *(uint4*)(hb + (size_t)id * 8) = pk;
    } else {
        int k = (b - 3780) * 256 + tid;
        if (k < N_EDGES) atomicAdd(&deg[ei[k]], 1);
    }
}

// ---------------- L2: fused st (s,t projections) + scan ----------------
__global__ void fused2_kernel(const float* __restrict__ h, const float* __restrict__ wa0,
                              const float* __restrict__ wa1,
                              float* __restrict__ s, float* __restrict__ t,
                              const int* __restrict__ deg, int* __restrict__ off,
                              int* __restrict__ cursor) {
    __shared__ int sb[256];
    int b = blockIdx.x;
    int tid = threadIdx.x;
    if (b < 2500) {
        int w = tid >> 6, l = tid & 63;
        int n = b * 4 + w;
        const float4* hp = (const float4*)(h + (size_t)n * IN_F);
        float4 hA = hp[l], hB = hp[l + 64];
        float4 wA0 = ((const float4*)wa0)[l], wB0 = ((const float4*)wa0)[l + 64];
        float4 wA1 = ((const float4*)wa1)[l], wB1 = ((const float4*)wa1)[l + 64];
        float ss = hA.x*wA0.x + hA.y*wA0.y + hA.z*wA0.z + hA.w*wA0.w
                 + hB.x*wB0.x + hB.y*wB0.y + hB.z*wB0.z + hB.w*wB0.w;
        float tt = hA.x*wA1.x + hA.y*wA1.y + hA.z*wA1.z + hA.w*wA1.w
                 + hB.x*wB1.x + hB.y*wB1.y + hB.z*wB1.z + hB.w*wB1.w;
        #pragma unroll
        for (int o = 32; o > 0; o >>= 1) {
            ss += __shfl_down(ss, o, 64);
            tt += __shfl_down(tt, o, 64);
        }
        if (l == 0) { s[n] = ss; t[n] = tt; }
    } else {
        int d[40];
        int tot = 0;
        #pragma unroll
        for (int j = 0; j < 40; ++j) {
            int idx = tid * 40 + j;
            d[j] = (idx < N_NODES) ? deg[idx] : 0;
            tot += d[j];
        }
        sb[tid] = tot;
        __syncthreads();
        for (int sd = 1; sd < 256; sd <<= 1) {
            int v = (tid >= sd) ? sb[tid - sd] : 0;
            __syncthreads();
            sb[tid] += v;
            __syncthreads();
        }
        int run = (tid > 0) ? sb[tid - 1] : 0;
        #pragma unroll
        for (int j = 0; j < 40; ++j) {
            int idx = tid * 40 + j;
            if (idx < N_NODES) { off[idx] = run; cursor[idx] = run; }
            run += d[j];
        }
        if (tid == 255) off[N_NODES] = sb[255];
    }
}

// ---------------- L3: fill CSR ----------------
__global__ void fill_kernel(const int* __restrict__ ei, int* __restrict__ cursor,
                            int* __restrict__ csr_col) {
    int k = blockIdx.x * 256 + threadIdx.x;
    if (k < N_EDGES) {
        int r = ei[k];
        int c = ei[N_EDGES + k];
        int p = atomicAdd(&cursor[r], 1);
        csr_col[p] = c;
    }
}

// ---------------- L4: segment softmax + aggregation, wave-per-node ----------------
__global__ __launch_bounds__(256) void agg_kernel(
    const ushort_t* __restrict__ hb, const float* __restrict__ s,
    const float* __restrict__ t, const int* __restrict__ off,
    const int* __restrict__ csr, float* __restrict__ agg) {
    int w = threadIdx.x >> 6, l = threadIdx.x & 63;
    int n = blockIdx.x * 4 + w;
    int e0 = off[n], e1 = off[n + 1];
    float sn = s[n];

    float m = -1e30f, den = 0.f;
    for (int k = e0 + l; k < e1; k += 64) {
        float v = sn + t[csr[k]];
        v = (v >= 0.f) ? v : ALPHA * v;
        float mn = fmaxf(m, v);
        den = den * __expf(m - mn) + __expf(v - mn);
        m = mn;
    }
    #pragma unroll
    for (int o = 1; o < 64; o <<= 1) {
        float m2 = __shfl_xor(m, o, 64);
        float d2 = __shfl_xor(den, o, 64);
        float mn = fmaxf(m, m2);
        den = den * __expf(m - mn) + d2 * __expf(m2 - mn);
        m = mn;
    }
    float inv = (den > 0.f) ? 1.f / den : 0.f;

    float acc[8] = {0.f, 0.f, 0.f, 0.f, 0.f, 0.f, 0.f, 0.f};
    const ushort_t* hbl = hb + l * 8;
    for (int base = e0; base < e1; base += 64) {
        int cnt = e1 - base; if (cnt > 64) cnt = 64;
        int c = 0; float att = 0.f;
        if (l < cnt) {
            c = csr[base + l];
            float v = sn + t[c];
            v = (v >= 0.f) ? v : ALPHA * v;
            att = __expf(v - m) * inv;
        }
        #pragma unroll 4
        for (int j = 0; j < cnt; ++j) {
            float aj = __shfl(att, j, 64);
            int cj = __shfl(c, j, 64);
            uint4 u = *(const uint4*)(hbl + (size_t)cj * IN_F);
            acc[0] = fmaf(aj, bflo(u.x), acc[0]);
            acc[1] = fmaf(aj, bfhi(u.x), acc[1]);
            acc[2] = fmaf(aj, bflo(u.y), acc[2]);
            acc[3] = fmaf(aj, bfhi(u.y), acc[3]);
            acc[4] = fmaf(aj, bflo(u.z), acc[4]);
            acc[5] = fmaf(aj, bfhi(u.z), acc[5]);
            acc[6] = fmaf(aj, bflo(u.w), acc[6]);
            acc[7] = fmaf(aj, bfhi(u.w), acc[7]);
        }
    }
    float* arow = agg + (size_t)n * IN_F + l * 8;
    *(float4*)arow       = make_float4(acc[0], acc[1], acc[2], acc[3]);
    *(float4*)(arow + 4) = make_float4(acc[4], acc[5], acc[6], acc[7]);
}

// ---------------- L5: expansion -> fragment-packed bf16 A (92.6 MB) ----------------
__global__ void expand_kernel(const float* __restrict__ agg, ushort_t* __restrict__ Xf) {
    int id = blockIdx.x * 256 + threadIdx.x;
    int l = id & 63;
    int fid = id >> 6;
    int nb = fid / NBK;
    int kb = fid - nb * NBK;
    int n = nb * 16 + (l & 15);
    uint4 pk = make_uint4(0u, 0u, 0u, 0u);
    if (n < N_NODES) {
        if (kb < 128) {
            int dim = kb * 4 + (l >> 4);
            pk = spline_window(agg[(size_t)n * IN_F + dim]);
        } else {
            const float* ap = agg + (size_t)n * IN_F + (kb - 128) * 32 + (l >> 4) * 8;
            float4 x0 = *(const float4*)ap;
            float4 x1 = *(const float4*)(ap + 4);
            pk.x = bfpair(silu_f(x0.x), silu_f(x0.y));
            pk.y = bfpair(silu_f(x0.z), silu_f(x0.w));
            pk.z = bfpair(silu_f(x1.x), silu_f(x1.y));
            pk.w = bfpair(silu_f(x1.z), silu_f(x1.w));
        }
    }
    *(uint4*)(Xf + (size_t)id * 8) = pk;
}

// ---------------- L6: streaming GEMM, BK=128, 2-phase double buffer ----------------
// BM=64, BN=128, 4 waves; 36 K-steps of 128; A via global_load_lds (16B);
// B direct L2->reg. Grid 640 XCD-swizzled: 4 bn-siblings of one bm share an
// XCD so the A-tile is HBM-fetched once and L2-hit 3x.
__global__ __launch_bounds__(256, 3) void kan_gemm2(
    const ushort_t* __restrict__ Xf, const ushort_t* __restrict__ Bt,
    float* __restrict__ out) {
    __shared__ ushort_t A_lds[2][4][4][64][8];   // 32 KB: [buf][ks][m][lane][8]

    int d = blockIdx.x;
    int g = d >> 5, r = d & 31;
    int bm = g * 8 + (r & 7), bn = r >> 3;
    if (bm >= 157) return;
    int tid = threadIdx.x, w = tid >> 6, l = tid & 63;
    int wc16 = bn * 8 + w * 2;

    f32x4 acc[4][2];
    #pragma unroll
    for (int m = 0; m < 4; ++m)
        #pragma unroll
        for (int nf = 0; nf < 2; ++nf)
            acc[m][nf] = (f32x4){0.f, 0.f, 0.f, 0.f};

    short8 b0[8], b1[8];

    auto stage = [&](int j, int pb) {            // A-tile for K-step j (4 kbs)
        #pragma unroll
        for (int ks = 0; ks < 4; ++ks) {
            const ushort_t* src = Xf + (((size_t)(bm * 4 + w) * NBK + 4 * j + ks) * 64 + l) * 8;
            __builtin_amdgcn_global_load_lds(
                (const __attribute__((address_space(1))) unsigned int*)src,
                (__attribute__((address_space(3))) unsigned int*)&A_lds[pb][ks][w][0][0],
                16, 0, 0);
        }
    };
    auto loadB = [&](int j, short8 (&b)[8]) {
        #pragma unroll
        for (int ks = 0; ks < 4; ++ks) {
            int kb = 4 * j + ks;
            b[ks * 2 + 0] = *(const short8*)(Bt + ((size_t)(kb * 32 + wc16)     * 64 + l) * 8);
            b[ks * 2 + 1] = *(const short8*)(Bt + ((size_t)(kb * 32 + wc16 + 1) * 64 + l) * 8);
        }
    };
    auto compute = [&](int pb, short8 (&b)[8]) {
        #pragma unroll
        for (int ks = 0; ks < 4; ++ks)
            #pragma unroll
            for (int m = 0; m < 4; ++m) {
                short8 af = *(const short8*)&A_lds[pb][ks][m][l][0];
                acc[m][0] = __builtin_amdgcn_mfma_f32_16x16x32_bf16(af, b[ks * 2 + 0], acc[m][0], 0, 0, 0);
                acc[m][1] = __builtin_amdgcn_mfma_f32_16x16x32_bf16(af, b[ks * 2 + 1], acc[m][1], 0, 0, 0);
            }
    };

    stage(0, 0);
    loadB(0, b0);
    __syncthreads();
    for (int j = 0; j < 36; j += 2) {
        if (j + 1 < 36) { stage(j + 1, 1); loadB(j + 1, b1); }
        compute(0, b0);
        __syncthreads();
        if (j + 2 < 36) { stage(j + 2, 0); loadB(j + 2, b0); }
        compute(1, b1);
        __syncthreads();
    }

    // store: C/D layout col = l&15, row = (l>>4)*4 + reg
    #pragma unroll
    for (int m = 0; m < 4; ++m) {
        int r0 = bm * 64 + m * 16 + ((l >> 4) << 2);
        #pragma unroll
        for (int nf = 0; nf < 2; ++nf) {
            int colg = bn * 128 + w * 32 + nf * 16 + (l & 15);
            #pragma unroll
            for (int jr = 0; jr < 4; ++jr) {
                int rr = r0 + jr;
                if (rr < N_NODES) out[(size_t)rr * OUT_F + colg] = acc[m][nf][jr];
            }
        }
    }
}

extern "C" void kernel_launch(void* const* d_in, const int* in_sizes, int n_in,
                              void* d_out, int out_size, void* d_ws, size_t ws_size,
                              hipStream_t stream) {
    const float* h        = (const float*)d_in[0];
    const float* W        = (const float*)d_in[1];
    const float* a        = (const float*)d_in[2];
    const float* base_w   = (const float*)d_in[3];
    const float* spline_w = (const float*)d_in[4];
    const int*   ei       = (const int*)d_in[5];
    float* out = (float*)d_out;

    char* ws = (char*)d_ws;
    size_t cur = 0;
    auto alloc = [&](size_t bytes) -> void* {
        void* p = ws + cur;
        cur += (bytes + 255) & ~(size_t)255;
        return p;
    };
    float* wa0    = (float*)alloc(512 * 4);
    float* wa1    = (float*)alloc(512 * 4);
    float* s      = (float*)alloc(N_NODES * 4);
    float* t      = (float*)alloc(N_NODES * 4);
    int*   deg    = (int*)alloc(N_NODES * 4);
    int*   offp   = (int*)alloc((N_NODES + 1) * 4);
    int*   cursor = (int*)alloc(N_NODES * 4);
    int*   csr    = (int*)alloc(N_EDGES * 4);
    float* agg    = (float*)alloc((size_t)N_NODES * IN_F * 4);
    ushort_t* Bt  = (ushort_t*)alloc((size_t)K_TOTAL * OUT_F * 2);
    ushort_t* hb  = (ushort_t*)alloc((size_t)N_NODES * IN_F * 2);
    ushort_t* Xf  = (ushort_t*)alloc((size_t)NBM * NBK * 64 * 16);
    if (cur > ws_size) return;

    hipMemsetAsync(deg, 0, N_NODES * 4, stream);
    fused1_kernel<<<4405, 256, 0, stream>>>(W, a, wa0, wa1, base_w, spline_w, Bt, h, hb, ei, deg);
    fused2_kernel<<<2501, 256, 0, stream>>>(h, wa0, wa1, s, t, deg, offp, cursor);
    fill_kernel<<<(N_EDGES + 255) / 256, 256, 0, stream>>>(ei, cursor, csr);
    agg_kernel<<<2500, 256, 0, stream>>>(hb, s, t, offp, csr, agg);
    expand_kernel<<<NBM * NBK * 64 / 256, 256, 0, stream>>>(agg, Xf);
    kan_gemm2<<<640, 256, 0, stream>>>(Xf, Bt, out);
}